// Round 10
// baseline (384.472 us; speedup 1.0000x reference)
//
#include <hip/hip_runtime.h>
#include <math.h>

#define NN 512
#define HD 256
#define NLAYER 6
#define QSCALE 0.17677669529663687f
#define ASTR 264   // padded activation LDS stride (shorts)

typedef __attribute__((ext_vector_type(8))) short bf16x8;
typedef __attribute__((ext_vector_type(4))) short bf16x4;
typedef __attribute__((ext_vector_type(4))) float f32x4;

__device__ __forceinline__ short f2bf(float f) {
  union { float f; unsigned u; } v; v.f = f;
  unsigned r = (v.u + 0x7FFFu + ((v.u >> 16) & 1u)) >> 16;
  return (short)r;
}
__device__ __forceinline__ float bf2f(short s) {
  union { unsigned u; float f; } v; v.u = ((unsigned)(unsigned short)s) << 16;
  return v.f;
}

// ---------- prep1: wcast (blocks 0..2367) + proj (2368..2527) ----------
__global__ __launch_bounds__(256) void prep1_kernel(
    const float* __restrict__ Wq, const float* __restrict__ Wk,
    const float* __restrict__ Wv, const float* __restrict__ Wo,
    const float* __restrict__ W1, const float* __restrict__ W2,
    const float* __restrict__ Wf,
    const float* __restrict__ edge_emb, const float* __restrict__ edge_dist_emb,
    const float* __restrict__ W_ee, const float* __restrict__ W_ed,
    short* __restrict__ Aqkv, short* __restrict__ AoT,
    short* __restrict__ A1T, short* __restrict__ A2T, short* __restrict__ WfT,
    float* __restrict__ eeP, float* __restrict__ edP) {
  int b = blockIdx.x, tid = threadIdx.x;
  if (b < 2368) {
    __shared__ float tile[32][33];
    const float* src; short* dst; float scl = 1.f;
    int t;
    if (b < 2304) {
      int l = b / 384; int rr = b % 384; int mat = rr / 64; t = rr % 64;
      if      (mat == 0) { src = Wq + l * 65536; dst = Aqkv + l * 196608; scl = QSCALE; }
      else if (mat == 1) { src = Wk + l * 65536; dst = Aqkv + l * 196608 + 65536; }
      else if (mat == 2) { src = Wv + l * 65536; dst = Aqkv + l * 196608 + 131072; }
      else if (mat == 3) { src = Wo + l * 65536; dst = AoT + l * 65536; }
      else if (mat == 4) { src = W1 + l * 65536; dst = A1T + l * 65536; }
      else               { src = W2 + l * 65536; dst = A2T + l * 65536; }
    } else {
      src = Wf; dst = WfT; t = b - 2304;
    }
    int tr = t >> 3, tc = t & 7;
    int kl = tid >> 3, nl4 = (tid & 7) * 4;
    float4 v = *(const float4*)(src + (tr * 32 + kl) * 256 + tc * 32 + nl4);
    tile[kl][nl4 + 0] = v.x; tile[kl][nl4 + 1] = v.y;
    tile[kl][nl4 + 2] = v.z; tile[kl][nl4 + 3] = v.w;
    __syncthreads();
    int nl = tid >> 3, kl4 = (tid & 7) * 4;
    bf16x4 o;
    #pragma unroll
    for (int i = 0; i < 4; i++) o[i] = f2bf(tile[kl4 + i][nl] * scl);
    *(bf16x4*)(dst + (tc * 32 + nl) * 256 + tr * 32 + kl4) = o;
  } else {
    int r = b - 2368;
    const float* table; const float* W; float* out; int row;
    if (r < 32) { table = edge_emb;      W = W_ee; out = eeP; row = r; }
    else        { table = edge_dist_emb; W = W_ed; out = edP; row = r - 32; }
    int w = tid >> 6, l = tid & 63;
    __shared__ float sb[4];
    float val = table[row * HD + tid];
    float ss = val * val;
    #pragma unroll
    for (int o = 32; o; o >>= 1) ss += __shfl_xor(ss, o);
    if (l == 0) sb[w] = ss;
    __syncthreads();
    ss = sb[0] + sb[1] + sb[2] + sb[3];
    float n = sqrtf(ss);
    float sc = (n > 1.f) ? 1.f / (n + 1e-7f) : 1.f;
    float v = val * sc;
    __syncthreads();
    #pragma unroll
    for (int hh = 0; hh < 8; hh++) {
      float p = v * W[tid * 8 + hh];
      #pragma unroll
      for (int o = 32; o; o >>= 1) p += __shfl_xor(p, o);
      if (l == 0) sb[w] = p;
      __syncthreads();
      if (tid == 0) out[row * 8 + hh] = sb[0] + sb[1] + sb[2] + sb[3];
      __syncthreads();
    }
  }
}

// ---------- prep2: bias (blocks 0..511) + feat+LN1+QKV0 (512..575) ----------
__global__ __launch_bounds__(512) void prep2_kernel(
    const int* __restrict__ ee, const int* __restrict__ ed,
    const float* __restrict__ eeP, const float* __restrict__ edP,
    const float* __restrict__ b_ee, const float* __restrict__ b_ed,
    short* __restrict__ bias_bf,
    const float* __restrict__ x, const short* __restrict__ WfT,
    const float* __restrict__ b_feat, float* __restrict__ h,
    const float* __restrict__ ln1_s, const float* __restrict__ ln1_b,
    const short* __restrict__ Aqkv, const float* __restrict__ bq,
    const float* __restrict__ bk, const float* __restrict__ bv,
    short* __restrict__ q_bf, short* __restrict__ k_bf, short* __restrict__ vT_bf) {
  __shared__ __align__(16) char lds_raw[17000];
  int tid = threadIdx.x, bid = blockIdx.x;
  if (bid < 512) {
    float* seeP = (float*)lds_raw;
    float* sedP = seeP + 256;
    float* sbe  = sedP + 1024;
    float* sbd  = sbe + 8;
    if (tid < 256) seeP[tid] = eeP[tid];
    sedP[tid] = edP[tid]; sedP[tid + 512] = edP[tid + 512];
    if (tid < 8) { sbe[tid] = b_ee[tid]; sbd[tid] = b_ed[tid]; }
    __syncthreads();
    int idx = bid * 512 + tid;
    int e0 = ee[idx * 2], e1 = ee[idx * 2 + 1];
    int d = ed[idx];
    #pragma unroll
    for (int hh = 0; hh < 8; hh++) {
      bias_bf[hh * (NN * NN) + idx] = f2bf(
          0.5f * (seeP[e0 * 8 + hh] + seeP[e1 * 8 + hh]) + sbe[hh]
          + sedP[d * 8 + hh] + sbd[hh]);
    }
    return;
  }
  // feat + LN1 + QKV layer 0, 8 rows/block
  short* Abuf = (short*)lds_raw;                  // [16][ASTR]
  float* hbuf = (float*)(lds_raw + 8448);         // [8][256]
  int w = tid >> 6, l = tid & 63, lr = l & 15, lk = l >> 4;
  int m0 = (bid - 512) * 8;
  if (tid < 264) {
    bf16x8 z = {};
    *(bf16x8*)(Abuf + 8 * ASTR + tid * 8) = z;
  }
  {
    int row = tid >> 6, j = tid & 63;
    float4 v = *(const float4*)(x + (m0 + row) * 256 + j * 4);
    bf16x4 o4; o4[0] = f2bf(v.x); o4[1] = f2bf(v.y); o4[2] = f2bf(v.z); o4[3] = f2bf(v.w);
    *(bf16x4*)(Abuf + row * ASTR + j * 4) = o4;
  }
  __syncthreads();
  {
    f32x4 acc[2] = {};
    int nb = w * 32;
    for (int k0 = 0; k0 < 256; k0 += 32) {
      bf16x8 af = *(const bf16x8*)(Abuf + lr * ASTR + k0 + lk * 8);
      bf16x8 b0 = *(const bf16x8*)(WfT + (nb + lr) * 256 + k0 + lk * 8);
      bf16x8 b1f = *(const bf16x8*)(WfT + (nb + 16 + lr) * 256 + k0 + lk * 8);
      acc[0] = __builtin_amdgcn_mfma_f32_16x16x32_bf16(af, b0, acc[0], 0, 0, 0);
      acc[1] = __builtin_amdgcn_mfma_f32_16x16x32_bf16(af, b1f, acc[1], 0, 0, 0);
    }
    #pragma unroll
    for (int t = 0; t < 2; t++) {
      int n = nb + t * 16 + lr;
      #pragma unroll
      for (int r = 0; r < 4; r++) {
        int m = lk * 4 + r;
        if (m < 8) {
          float v = acc[t][r] + b_feat[n];
          hbuf[m * 256 + n] = v;
          h[(m0 + m) * 256 + n] = v;
        }
      }
    }
  }
  __syncthreads();
  {  // LN1: wave w -> row w
    float4 v4 = *(const float4*)(hbuf + w * 256 + l * 4);
    float sum = v4.x + v4.y + v4.z + v4.w;
    #pragma unroll
    for (int o = 32; o; o >>= 1) sum += __shfl_xor(sum, o);
    float mean = sum * (1.f / 256.f);
    float dx = v4.x - mean, dy = v4.y - mean, dz = v4.z - mean, dw = v4.w - mean;
    float var = dx * dx + dy * dy + dz * dz + dw * dw;
    #pragma unroll
    for (int o = 32; o; o >>= 1) var += __shfl_xor(var, o);
    float inv = rsqrtf(var * (1.f / 256.f) + 1e-5f);
    const float4 sv = *(const float4*)(ln1_s + l * 4);
    const float4 bv4 = *(const float4*)(ln1_b + l * 4);
    bf16x4 o4;
    o4[0] = f2bf(dx * inv * sv.x + bv4.x);
    o4[1] = f2bf(dy * inv * sv.y + bv4.y);
    o4[2] = f2bf(dz * inv * sv.z + bv4.z);
    o4[3] = f2bf(dw * inv * sv.w + bv4.w);
    *(bf16x4*)(Abuf + w * ASTR + l * 4) = o4;
  }
  __syncthreads();
  {  // QKV layer 0
    f32x4 acc[6] = {};
    int nb = w * 96;
    for (int k0 = 0; k0 < 256; k0 += 32) {
      bf16x8 af = *(const bf16x8*)(Abuf + lr * ASTR + k0 + lk * 8);
      #pragma unroll
      for (int t = 0; t < 6; t++) {
        bf16x8 bfr = *(const bf16x8*)(Aqkv + (nb + t * 16 + lr) * 256 + k0 + lk * 8);
        acc[t] = __builtin_amdgcn_mfma_f32_16x16x32_bf16(af, bfr, acc[t], 0, 0, 0);
      }
    }
    #pragma unroll
    for (int t = 0; t < 6; t++) {
      int n = nb + t * 16 + lr;
      #pragma unroll
      for (int r = 0; r < 4; r++) {
        int m = lk * 4 + r;
        if (m < 8) {
          int gm = m0 + m;
          float v = acc[t][r];
          if (n < 256) {
            q_bf[((n >> 5) * 512 + gm) * 32 + (n & 31)] = f2bf(v + bq[n] * QSCALE);
          } else if (n < 512) {
            int nn = n - 256;
            k_bf[((nn >> 5) * 512 + gm) * 32 + (nn & 31)] = f2bf(v + bk[nn]);
          } else {
            int nn = n - 512;
            vT_bf[nn * 512 + gm] = f2bf(v + bv[nn]);
          }
        }
      }
    }
  }
}

// ---------- layer: attn (4 rows x 8 heads) + tail, 128 blocks x 512 ----------
__global__ __launch_bounds__(512) void layer_kernel(
    const short* __restrict__ qin, const short* __restrict__ kin,
    const short* __restrict__ vin, const short* __restrict__ bias_bf,
    float* __restrict__ h,
    const short* __restrict__ AoT_l, const float* __restrict__ bo_l,
    const float* __restrict__ ln2_s, const float* __restrict__ ln2_b,
    const short* __restrict__ A1T_l, const float* __restrict__ b1_l,
    const short* __restrict__ A2T_l, const float* __restrict__ b2_l,
    const float* __restrict__ ln1n_s, const float* __restrict__ ln1n_b,
    const short* __restrict__ Aqkv_n, const float* __restrict__ bq_n,
    const float* __restrict__ bk_n, const float* __restrict__ bv_n,
    short* __restrict__ qo, short* __restrict__ ko, short* __restrict__ vo,
    int last) {
  __shared__ __align__(16) short S[32 * 520];     // bias -> logits -> P
  __shared__ __align__(16) short Abuf[16 * ASTR];
  __shared__ __align__(16) short Bbuf[16 * ASTR];
  __shared__ __align__(16) float hbuf[4 * 256];
  int tid = threadIdx.x, bid = blockIdx.x;
  int w = tid >> 6, l = tid & 63, lr = l & 15, lk = l >> 4;
  int m0 = bid * 4;

  // zero pad rows 4..15 of Abuf, Bbuf
  for (int i = tid; i < 792; i += 512) {
    bf16x8 z = {};
    if (i < 396) *(bf16x8*)(Abuf + 4 * ASTR + i * 8) = z;
    else         *(bf16x8*)(Bbuf + 4 * ASTR + (i - 396) * 8) = z;
  }
  // stage bias tile: S[(hh*4+r)*520 + node] = bias[(hh*512 + m0+r)*512 + node]
  for (int i = tid; i < 2048; i += 512) {
    int row = i >> 6, grp = i & 63;
    *(bf16x8*)(S + row * 520 + grp * 8) =
        *(const bf16x8*)(bias_bf + (((row >> 2) * 512) + m0 + (row & 3)) * 512 + grp * 8);
  }
  __syncthreads();

  // QK^T: wave w = head w; 4 valid rows (pad to 16 in MFMA M)
  {
    int qrow = m0 + lr; if (qrow > 511) qrow = 511;
    bf16x8 aq = *(const bf16x8*)(qin + (w * 512 + qrow) * 32 + lk * 8);
    #pragma unroll 4
    for (int j = 0; j < 32; j++) {
      bf16x8 bk8 = *(const bf16x8*)(kin + (w * 512 + j * 16 + lr) * 32 + lk * 8);
      f32x4 s = {};
      s = __builtin_amdgcn_mfma_f32_16x16x32_bf16(aq, bk8, s, 0, 0, 0);
      int gnode = j * 16 + lr;
      #pragma unroll
      for (int r = 0; r < 4; r++) {
        int row = lk * 4 + r;
        if (row < 4) {
          short* sp = S + (w * 4 + row) * 520 + gnode;
          *sp = f2bf(s[r] + bf2f(*sp));
        }
      }
    }
  }
  __syncthreads();

  // softmax: 32 rows, 16 threads/row
  {
    int rr = tid >> 4, j = tid & 15;
    short* Srow = S + rr * 520;
    float mx = -1e30f;
    #pragma unroll 8
    for (int t = 0; t < 32; t++) mx = fmaxf(mx, bf2f(Srow[j + t * 16]));
    #pragma unroll
    for (int o = 8; o; o >>= 1) mx = fmaxf(mx, __shfl_xor(mx, o, 16));
    float sum = 0.f;
    #pragma unroll 8
    for (int t = 0; t < 32; t++) sum += __expf(bf2f(Srow[j + t * 16]) - mx);
    #pragma unroll
    for (int o = 8; o; o >>= 1) sum += __shfl_xor(sum, o, 16);
    float inv = 1.f / sum;
    #pragma unroll 8
    for (int t = 0; t < 32; t++)
      Srow[j + t * 16] = f2bf(__expf(bf2f(Srow[j + t * 16]) - mx) * inv);
  }
  __syncthreads();

  // PV: wave w = head w, both dk halves
  #pragma unroll
  for (int dh = 0; dh < 2; dh++) {
    f32x4 oc = {};
    #pragma unroll 4
    for (int ch = 0; ch < 16; ch++) {
      bf16x8 ap = *(const bf16x8*)(S + (w * 4 + lr) * 520 + ch * 32 + lk * 8);
      bf16x8 bv8 = *(const bf16x8*)(vin + (w * 32 + dh * 16 + lr) * 512 + ch * 32 + lk * 8);
      oc = __builtin_amdgcn_mfma_f32_16x16x32_bf16(ap, bv8, oc, 0, 0, 0);
    }
    #pragma unroll
    for (int r = 0; r < 4; r++) {
      int row = lk * 4 + r;
      if (row < 4)
        Abuf[row * ASTR + w * 32 + dh * 16 + lr] = f2bf(oc[r]);
    }
  }
  __syncthreads();

  // O-proj + residual
  {
    f32x4 acc[2] = {};
    int nb = w * 32;
    for (int k0 = 0; k0 < 256; k0 += 32) {
      bf16x8 af = *(const bf16x8*)(Abuf + lr * ASTR + k0 + lk * 8);
      bf16x8 b0 = *(const bf16x8*)(AoT_l + (nb + lr) * 256 + k0 + lk * 8);
      bf16x8 b1f = *(const bf16x8*)(AoT_l + (nb + 16 + lr) * 256 + k0 + lk * 8);
      acc[0] = __builtin_amdgcn_mfma_f32_16x16x32_bf16(af, b0, acc[0], 0, 0, 0);
      acc[1] = __builtin_amdgcn_mfma_f32_16x16x32_bf16(af, b1f, acc[1], 0, 0, 0);
    }
    #pragma unroll
    for (int t = 0; t < 2; t++) {
      int n = nb + t * 16 + lr;
      #pragma unroll
      for (int r = 0; r < 4; r++) {
        int m = lk * 4 + r;
        if (m < 4) {
          float hv = h[(m0 + m) * 256 + n] + acc[t][r] + bo_l[n];
          hbuf[m * 256 + n] = hv;
          h[(m0 + m) * 256 + n] = hv;
        }
      }
    }
  }
  __syncthreads();
  // LN2 (waves 0-3)
  if (w < 4) {
    float4 v4 = *(const float4*)(hbuf + w * 256 + l * 4);
    float sum = v4.x + v4.y + v4.z + v4.w;
    #pragma unroll
    for (int o = 32; o; o >>= 1) sum += __shfl_xor(sum, o);
    float mean = sum * (1.f / 256.f);
    float dx = v4.x - mean, dy = v4.y - mean, dz = v4.z - mean, dw = v4.w - mean;
    float var = dx * dx + dy * dy + dz * dz + dw * dw;
    #pragma unroll
    for (int o = 32; o; o >>= 1) var += __shfl_xor(var, o);
    float inv = rsqrtf(var * (1.f / 256.f) + 1e-5f);
    const float4 sv = *(const float4*)(ln2_s + l * 4);
    const float4 bv4 = *(const float4*)(ln2_b + l * 4);
    bf16x4 o4;
    o4[0] = f2bf(dx * inv * sv.x + bv4.x);
    o4[1] = f2bf(dy * inv * sv.y + bv4.y);
    o4[2] = f2bf(dz * inv * sv.z + bv4.z);
    o4[3] = f2bf(dw * inv * sv.w + bv4.w);
    *(bf16x4*)(Abuf + w * ASTR + l * 4) = o4;
  }
  __syncthreads();
  // FFN1 + gelu
  {
    f32x4 acc[2] = {};
    int nb = w * 32;
    for (int k0 = 0; k0 < 256; k0 += 32) {
      bf16x8 af = *(const bf16x8*)(Abuf + lr * ASTR + k0 + lk * 8);
      bf16x8 b0 = *(const bf16x8*)(A1T_l + (nb + lr) * 256 + k0 + lk * 8);
      bf16x8 b1f = *(const bf16x8*)(A1T_l + (nb + 16 + lr) * 256 + k0 + lk * 8);
      acc[0] = __builtin_amdgcn_mfma_f32_16x16x32_bf16(af, b0, acc[0], 0, 0, 0);
      acc[1] = __builtin_amdgcn_mfma_f32_16x16x32_bf16(af, b1f, acc[1], 0, 0, 0);
    }
    #pragma unroll
    for (int t = 0; t < 2; t++) {
      int n = nb + t * 16 + lr;
      #pragma unroll
      for (int r = 0; r < 4; r++) {
        int m = lk * 4 + r;
        if (m < 4) {
          float val = acc[t][r] + b1_l[n];
          Bbuf[m * ASTR + n] =
              f2bf(0.5f * val * (1.f + erff(val * 0.70710678118654752f)));
        }
      }
    }
  }
  __syncthreads();
  // FFN2 + residual
  {
    f32x4 acc[2] = {};
    int nb = w * 32;
    for (int k0 = 0; k0 < 256; k0 += 32) {
      bf16x8 af = *(const bf16x8*)(Bbuf + lr * ASTR + k0 + lk * 8);
      bf16x8 b0 = *(const bf16x8*)(A2T_l + (nb + lr) * 256 + k0 + lk * 8);
      bf16x8 b1f = *(const bf16x8*)(A2T_l + (nb + 16 + lr) * 256 + k0 + lk * 8);
      acc[0] = __builtin_amdgcn_mfma_f32_16x16x32_bf16(af, b0, acc[0], 0, 0, 0);
      acc[1] = __builtin_amdgcn_mfma_f32_16x16x32_bf16(af, b1f, acc[1], 0, 0, 0);
    }
    #pragma unroll
    for (int t = 0; t < 2; t++) {
      int n = nb + t * 16 + lr;
      #pragma unroll
      for (int r = 0; r < 4; r++) {
        int m = lk * 4 + r;
        if (m < 4) {
          float hv = hbuf[m * 256 + n] + acc[t][r] + b2_l[n];
          h[(m0 + m) * 256 + n] = hv;
          hbuf[m * 256 + n] = hv;
        }
      }
    }
  }
  if (last) return;
  __syncthreads();
  // LN1 next (waves 0-3)
  if (w < 4) {
    float4 v4 = *(const float4*)(hbuf + w * 256 + l * 4);
    float sum = v4.x + v4.y + v4.z + v4.w;
    #pragma unroll
    for (int o = 32; o; o >>= 1) sum += __shfl_xor(sum, o);
    float mean = sum * (1.f / 256.f);
    float dx = v4.x - mean, dy = v4.y - mean, dz = v4.z - mean, dw = v4.w - mean;
    float var = dx * dx + dy * dy + dz * dz + dw * dw;
    #pragma unroll
    for (int o = 32; o; o >>= 1) var += __shfl_xor(var, o);
    float inv = rsqrtf(var * (1.f / 256.f) + 1e-5f);
    const float4 sv = *(const float4*)(ln1n_s + l * 4);
    const float4 bv4 = *(const float4*)(ln1n_b + l * 4);
    bf16x4 o4;
    o4[0] = f2bf(dx * inv * sv.x + bv4.x);
    o4[1] = f2bf(dy * inv * sv.y + bv4.y);
    o4[2] = f2bf(dz * inv * sv.z + bv4.z);
    o4[3] = f2bf(dw * inv * sv.w + bv4.w);
    *(bf16x4*)(Abuf + w * ASTR + l * 4) = o4;
  }
  __syncthreads();
  // QKV next layer -> parity-out buffers
  {
    f32x4 acc[6] = {};
    int nb = w * 96;
    for (int k0 = 0; k0 < 256; k0 += 32) {
      bf16x8 af = *(const bf16x8*)(Abuf + lr * ASTR + k0 + lk * 8);
      #pragma unroll
      for (int t = 0; t < 6; t++) {
        bf16x8 bfr = *(const bf16x8*)(Aqkv_n + (nb + t * 16 + lr) * 256 + k0 + lk * 8);
        acc[t] = __builtin_amdgcn_mfma_f32_16x16x32_bf16(af, bfr, acc[t], 0, 0, 0);
      }
    }
    #pragma unroll
    for (int t = 0; t < 6; t++) {
      int n = nb + t * 16 + lr;
      #pragma unroll
      for (int r = 0; r < 4; r++) {
        int m = lk * 4 + r;
        if (m < 4) {
          int gm = m0 + m;
          float v = acc[t][r];
          if (n < 256) {
            qo[((n >> 5) * 512 + gm) * 32 + (n & 31)] = f2bf(v + bq_n[n] * QSCALE);
          } else if (n < 512) {
            int nn = n - 256;
            ko[((nn >> 5) * 512 + gm) * 32 + (nn & 31)] = f2bf(v + bk_n[nn]);
          } else {
            int nn = n - 512;
            vo[nn * 512 + gm] = f2bf(v + bv_n[nn]);
          }
        }
      }
    }
  }
}

extern "C" void kernel_launch(void* const* d_in, const int* in_sizes, int n_in,
                              void* d_out, int out_size, void* d_ws, size_t ws_size,
                              hipStream_t stream) {
  const float* x             = (const float*)d_in[0];
  const int*   edge_encodes  = (const int*)d_in[2];
  const int*   edge_dist_enc = (const int*)d_in[3];
  const float* W_feat = (const float*)d_in[7];
  const float* b_feat = (const float*)d_in[8];
  const float* edge_emb      = (const float*)d_in[9];
  const float* edge_dist_emb = (const float*)d_in[10];
  const float* W_ee = (const float*)d_in[11];
  const float* b_ee = (const float*)d_in[12];
  const float* W_ed = (const float*)d_in[13];
  const float* b_ed = (const float*)d_in[14];
  const float* ln1_s = (const float*)d_in[15];
  const float* ln1_b = (const float*)d_in[16];
  const float* Wq = (const float*)d_in[17];
  const float* bq = (const float*)d_in[18];
  const float* Wk = (const float*)d_in[19];
  const float* bk = (const float*)d_in[20];
  const float* Wv = (const float*)d_in[21];
  const float* bv = (const float*)d_in[22];
  const float* Wo = (const float*)d_in[23];
  const float* bo = (const float*)d_in[24];
  const float* ln2_s = (const float*)d_in[25];
  const float* ln2_b = (const float*)d_in[26];
  const float* W1 = (const float*)d_in[27];
  const float* b1 = (const float*)d_in[28];
  const float* W2 = (const float*)d_in[29];
  const float* b2 = (const float*)d_in[30];

  float* h = (float*)d_out;
  char* base = (char*)d_ws;
  short* bias_bf = (short*)base;                       // 4 MB
  short* Aqkv = (short*)(base + 4194304);
  short* AoT  = (short*)(base + 6553600);
  short* A1T  = (short*)(base + 7340032);
  short* A2T  = (short*)(base + 8126464);
  short* WfT  = (short*)(base + 8912896);
  short* qkv0 = (short*)(base + 9043968);              // parity 0: q,k,vT
  short* qkv1 = (short*)(base + 9830400);              // parity 1
  float* eeP  = (float*)(base + 10616832);
  float* edP  = (float*)(base + 10617856);

  short* q0 = qkv0, *k0 = qkv0 + 131072, *v0 = qkv0 + 262144;
  short* q1 = qkv1, *k1 = qkv1 + 131072, *v1 = qkv1 + 262144;

  prep1_kernel<<<2528, 256, 0, stream>>>(
      Wq, Wk, Wv, Wo, W1, W2, W_feat,
      edge_emb, edge_dist_emb, W_ee, W_ed,
      Aqkv, AoT, A1T, A2T, WfT, eeP, edP);
  prep2_kernel<<<576, 512, 0, stream>>>(
      edge_encodes, edge_dist_enc, eeP, edP, b_ee, b_ed, bias_bf,
      x, WfT, b_feat, h, ln1_s, ln1_b, Aqkv, bq, bk, bv, q0, k0, v0);

  for (int l = 0; l < NLAYER; l++) {
    int p = l & 1;
    short* qi = p ? q1 : q0; short* ki = p ? k1 : k0; short* vi = p ? v1 : v0;
    short* qq = p ? q0 : q1; short* kk = p ? k0 : k1; short* vv = p ? v0 : v1;
    int ln = (l < NLAYER - 1) ? l + 1 : l;
    layer_kernel<<<128, 512, 0, stream>>>(
        qi, ki, vi, bias_bf, h,
        AoT + l * 65536, bo + l * HD,
        ln2_s + l * HD, ln2_b + l * HD,
        A1T + l * 65536, b1 + l * HD,
        A2T + l * 65536, b2 + l * HD,
        ln1_s + ln * HD, ln1_b + ln * HD,
        Aqkv + ln * 196608, bq + ln * HD, bk + ln * HD, bv + ln * HD,
        qq, kk, vv, l == NLAYER - 1);
  }
}

// Round 11
// 261.852 us; speedup vs baseline: 1.4683x; 1.4683x over previous
//
#include <hip/hip_runtime.h>
#include <math.h>

#define NN 512
#define HD 256
#define NLAYER 6
#define QSCALE 0.17677669529663687f
#define ASTR 264   // padded activation LDS stride (shorts)

typedef __attribute__((ext_vector_type(8))) short bf16x8;
typedef __attribute__((ext_vector_type(4))) short bf16x4;
typedef __attribute__((ext_vector_type(4))) float f32x4;

__device__ __forceinline__ short f2bf(float f) {
  union { float f; unsigned u; } v; v.f = f;
  unsigned r = (v.u + 0x7FFFu + ((v.u >> 16) & 1u)) >> 16;
  return (short)r;
}
__device__ __forceinline__ float bf2f(short s) {
  union { unsigned u; float f; } v; v.u = ((unsigned)(unsigned short)s) << 16;
  return v.f;
}

// ---------- prep1: wcast (blocks 0..2367) + proj (2368..2527) ----------
__global__ __launch_bounds__(256) void prep1_kernel(
    const float* __restrict__ Wq, const float* __restrict__ Wk,
    const float* __restrict__ Wv, const float* __restrict__ Wo,
    const float* __restrict__ W1, const float* __restrict__ W2,
    const float* __restrict__ Wf,
    const float* __restrict__ edge_emb, const float* __restrict__ edge_dist_emb,
    const float* __restrict__ W_ee, const float* __restrict__ W_ed,
    short* __restrict__ Aqkv, short* __restrict__ AoT,
    short* __restrict__ A1T, short* __restrict__ A2T, short* __restrict__ WfT,
    float* __restrict__ eeP, float* __restrict__ edP) {
  int b = blockIdx.x, tid = threadIdx.x;
  if (b < 2368) {
    __shared__ float tile[32][33];
    const float* src; short* dst; float scl = 1.f;
    int t;
    if (b < 2304) {
      int l = b / 384; int rr = b % 384; int mat = rr / 64; t = rr % 64;
      if      (mat == 0) { src = Wq + l * 65536; dst = Aqkv + l * 196608; scl = QSCALE; }
      else if (mat == 1) { src = Wk + l * 65536; dst = Aqkv + l * 196608 + 65536; }
      else if (mat == 2) { src = Wv + l * 65536; dst = Aqkv + l * 196608 + 131072; }
      else if (mat == 3) { src = Wo + l * 65536; dst = AoT + l * 65536; }
      else if (mat == 4) { src = W1 + l * 65536; dst = A1T + l * 65536; }
      else               { src = W2 + l * 65536; dst = A2T + l * 65536; }
    } else {
      src = Wf; dst = WfT; t = b - 2304;
    }
    int tr = t >> 3, tc = t & 7;
    int kl = tid >> 3, nl4 = (tid & 7) * 4;
    float4 v = *(const float4*)(src + (tr * 32 + kl) * 256 + tc * 32 + nl4);
    tile[kl][nl4 + 0] = v.x; tile[kl][nl4 + 1] = v.y;
    tile[kl][nl4 + 2] = v.z; tile[kl][nl4 + 3] = v.w;
    __syncthreads();
    int nl = tid >> 3, kl4 = (tid & 7) * 4;
    bf16x4 o;
    #pragma unroll
    for (int i = 0; i < 4; i++) o[i] = f2bf(tile[kl4 + i][nl] * scl);
    *(bf16x4*)(dst + (tc * 32 + nl) * 256 + tr * 32 + kl4) = o;
  } else {
    int r = b - 2368;
    const float* table; const float* W; float* out; int row;
    if (r < 32) { table = edge_emb;      W = W_ee; out = eeP; row = r; }
    else        { table = edge_dist_emb; W = W_ed; out = edP; row = r - 32; }
    int w = tid >> 6, l = tid & 63;
    __shared__ float sb[4];
    float val = table[row * HD + tid];
    float ss = val * val;
    #pragma unroll
    for (int o = 32; o; o >>= 1) ss += __shfl_xor(ss, o);
    if (l == 0) sb[w] = ss;
    __syncthreads();
    ss = sb[0] + sb[1] + sb[2] + sb[3];
    float n = sqrtf(ss);
    float sc = (n > 1.f) ? 1.f / (n + 1e-7f) : 1.f;
    float v = val * sc;
    __syncthreads();
    #pragma unroll
    for (int hh = 0; hh < 8; hh++) {
      float p = v * W[tid * 8 + hh];
      #pragma unroll
      for (int o = 32; o; o >>= 1) p += __shfl_xor(p, o);
      if (l == 0) sb[w] = p;
      __syncthreads();
      if (tid == 0) out[row * 8 + hh] = sb[0] + sb[1] + sb[2] + sb[3];
      __syncthreads();
    }
  }
}

// ---------- prep2: bias (blocks 0..511) + feat+LN1+QKV0 (512..575) ----------
__global__ __launch_bounds__(512) void prep2_kernel(
    const int* __restrict__ ee, const int* __restrict__ ed,
    const float* __restrict__ eeP, const float* __restrict__ edP,
    const float* __restrict__ b_ee, const float* __restrict__ b_ed,
    short* __restrict__ bias_bf,
    const float* __restrict__ x, const short* __restrict__ WfT,
    const float* __restrict__ b_feat, float* __restrict__ h,
    const float* __restrict__ ln1_s, const float* __restrict__ ln1_b,
    const short* __restrict__ Aqkv, const float* __restrict__ bq,
    const float* __restrict__ bk, const float* __restrict__ bv,
    short* __restrict__ q_bf, short* __restrict__ k_bf, short* __restrict__ vT_bf) {
  __shared__ __align__(16) char lds_raw[17000];
  int tid = threadIdx.x, bid = blockIdx.x;
  if (bid < 512) {
    float* seeP = (float*)lds_raw;
    float* sedP = seeP + 256;
    float* sbe  = sedP + 1024;
    float* sbd  = sbe + 8;
    if (tid < 256) seeP[tid] = eeP[tid];
    sedP[tid] = edP[tid]; sedP[tid + 512] = edP[tid + 512];
    if (tid < 8) { sbe[tid] = b_ee[tid]; sbd[tid] = b_ed[tid]; }
    __syncthreads();
    int idx = bid * 512 + tid;
    int e0 = ee[idx * 2], e1 = ee[idx * 2 + 1];
    int d = ed[idx];
    #pragma unroll
    for (int hh = 0; hh < 8; hh++) {
      bias_bf[hh * (NN * NN) + idx] = f2bf(
          0.5f * (seeP[e0 * 8 + hh] + seeP[e1 * 8 + hh]) + sbe[hh]
          + sedP[d * 8 + hh] + sbd[hh]);
    }
    return;
  }
  short* Abuf = (short*)lds_raw;                  // [16][ASTR]
  float* hbuf = (float*)(lds_raw + 8448);         // [8][256]
  int w = tid >> 6, l = tid & 63, lr = l & 15, lk = l >> 4;
  int m0 = (bid - 512) * 8;
  if (tid < 264) {
    bf16x8 z = {};
    *(bf16x8*)(Abuf + 8 * ASTR + tid * 8) = z;
  }
  {
    int row = tid >> 6, j = tid & 63;
    float4 v = *(const float4*)(x + (m0 + row) * 256 + j * 4);
    bf16x4 o4; o4[0] = f2bf(v.x); o4[1] = f2bf(v.y); o4[2] = f2bf(v.z); o4[3] = f2bf(v.w);
    *(bf16x4*)(Abuf + row * ASTR + j * 4) = o4;
  }
  __syncthreads();
  {
    f32x4 acc[2] = {};
    int nb = w * 32;
    for (int k0 = 0; k0 < 256; k0 += 32) {
      bf16x8 af = *(const bf16x8*)(Abuf + lr * ASTR + k0 + lk * 8);
      bf16x8 b0 = *(const bf16x8*)(WfT + (nb + lr) * 256 + k0 + lk * 8);
      bf16x8 b1f = *(const bf16x8*)(WfT + (nb + 16 + lr) * 256 + k0 + lk * 8);
      acc[0] = __builtin_amdgcn_mfma_f32_16x16x32_bf16(af, b0, acc[0], 0, 0, 0);
      acc[1] = __builtin_amdgcn_mfma_f32_16x16x32_bf16(af, b1f, acc[1], 0, 0, 0);
    }
    #pragma unroll
    for (int t = 0; t < 2; t++) {
      int n = nb + t * 16 + lr;
      #pragma unroll
      for (int r = 0; r < 4; r++) {
        int m = lk * 4 + r;
        if (m < 8) {
          float v = acc[t][r] + b_feat[n];
          hbuf[m * 256 + n] = v;
          h[(m0 + m) * 256 + n] = v;
        }
      }
    }
  }
  __syncthreads();
  {  // LN1: wave w -> row w
    float4 v4 = *(const float4*)(hbuf + w * 256 + l * 4);
    float sum = v4.x + v4.y + v4.z + v4.w;
    #pragma unroll
    for (int o = 32; o; o >>= 1) sum += __shfl_xor(sum, o);
    float mean = sum * (1.f / 256.f);
    float dx = v4.x - mean, dy = v4.y - mean, dz = v4.z - mean, dw = v4.w - mean;
    float var = dx * dx + dy * dy + dz * dz + dw * dw;
    #pragma unroll
    for (int o = 32; o; o >>= 1) var += __shfl_xor(var, o);
    float inv = rsqrtf(var * (1.f / 256.f) + 1e-5f);
    const float4 sv = *(const float4*)(ln1_s + l * 4);
    const float4 bv4 = *(const float4*)(ln1_b + l * 4);
    bf16x4 o4;
    o4[0] = f2bf(dx * inv * sv.x + bv4.x);
    o4[1] = f2bf(dy * inv * sv.y + bv4.y);
    o4[2] = f2bf(dz * inv * sv.z + bv4.z);
    o4[3] = f2bf(dw * inv * sv.w + bv4.w);
    *(bf16x4*)(Abuf + w * ASTR + l * 4) = o4;
  }
  __syncthreads();
  {  // QKV layer 0
    f32x4 acc[6] = {};
    int nb = w * 96;
    for (int k0 = 0; k0 < 256; k0 += 32) {
      bf16x8 af = *(const bf16x8*)(Abuf + lr * ASTR + k0 + lk * 8);
      #pragma unroll
      for (int t = 0; t < 6; t++) {
        bf16x8 bfr = *(const bf16x8*)(Aqkv + (nb + t * 16 + lr) * 256 + k0 + lk * 8);
        acc[t] = __builtin_amdgcn_mfma_f32_16x16x32_bf16(af, bfr, acc[t], 0, 0, 0);
      }
    }
    #pragma unroll
    for (int t = 0; t < 6; t++) {
      int n = nb + t * 16 + lr;
      #pragma unroll
      for (int r = 0; r < 4; r++) {
        int m = lk * 4 + r;
        if (m < 8) {
          int gm = m0 + m;
          float v = acc[t][r];
          if (n < 256) {
            q_bf[((n >> 5) * 512 + gm) * 32 + (n & 31)] = f2bf(v + bq[n] * QSCALE);
          } else if (n < 512) {
            int nn = n - 256;
            k_bf[((nn >> 5) * 512 + gm) * 32 + (nn & 31)] = f2bf(v + bk[nn]);
          } else {
            int nn = n - 512;
            vT_bf[nn * 512 + gm] = f2bf(v + bv[nn]);
          }
        }
      }
    }
  }
}

// ---------- attention: 256 blocks x 256 threads, 1 (head, rowtile16) ----------
__global__ __launch_bounds__(256) void attn_kernel(
    const short* __restrict__ q_bf, const short* __restrict__ k_bf,
    const short* __restrict__ vT_bf, const short* __restrict__ bias_bf,
    short* __restrict__ o_bf) {
  __shared__ __align__(16) short S[16 * 520];
  int tid = threadIdx.x, bid = blockIdx.x;
  int w = tid >> 6, l = tid & 63, lr = l & 15, lk = l >> 4;
  int head = bid >> 5, rt = bid & 31;
  // stage bias tile (coalesced)
  for (int i = tid; i < 1024; i += 256) {
    int row = i >> 6, grp = i & 63;
    *(bf16x8*)(S + row * 520 + grp * 8) =
        *(const bf16x8*)(bias_bf + (head * 512 + rt * 16 + row) * 512 + grp * 8);
  }
  bf16x8 aq = *(const bf16x8*)(q_bf + (head * 512 + rt * 16 + lr) * 32 + lk * 8);
  __syncthreads();
  // QK^T + bias (wave w covers node quarter w)
  #pragma unroll 2
  for (int j = 0; j < 8; j++) {
    int node0 = w * 128 + j * 16;
    bf16x8 bk8 = *(const bf16x8*)(k_bf + (head * 512 + node0 + lr) * 32 + lk * 8);
    f32x4 s = {};
    s = __builtin_amdgcn_mfma_f32_16x16x32_bf16(aq, bk8, s, 0, 0, 0);
    int gnode = node0 + lr;
    #pragma unroll
    for (int r = 0; r < 4; r++) {
      int row = lk * 4 + r;
      short* sp = S + row * 520 + gnode;
      *sp = f2bf(s[r] + bf2f(*sp));
    }
  }
  __syncthreads();
  // softmax: 16 rows, 16 threads/row
  {
    int row = tid >> 4, j = tid & 15;
    short* Srow = S + row * 520;
    float mx = -1e30f;
    #pragma unroll 8
    for (int t = 0; t < 32; t++) mx = fmaxf(mx, bf2f(Srow[j + t * 16]));
    #pragma unroll
    for (int o = 8; o; o >>= 1) mx = fmaxf(mx, __shfl_xor(mx, o, 16));
    float sum = 0.f;
    #pragma unroll 8
    for (int t = 0; t < 32; t++) sum += __expf(bf2f(Srow[j + t * 16]) - mx);
    #pragma unroll
    for (int o = 8; o; o >>= 1) sum += __shfl_xor(sum, o, 16);
    float inv = 1.f / sum;
    #pragma unroll 8
    for (int t = 0; t < 32; t++)
      Srow[j + t * 16] = f2bf(__expf(bf2f(Srow[j + t * 16]) - mx) * inv);
  }
  __syncthreads();
  // PV: waves 0,1 -> dk halves
  if (w < 2) {
    int dh = w;
    f32x4 oc = {};
    #pragma unroll 4
    for (int ch = 0; ch < 16; ch++) {
      bf16x8 ap = *(const bf16x8*)(S + lr * 520 + ch * 32 + lk * 8);
      bf16x8 bv8 = *(const bf16x8*)(vT_bf + (head * 32 + dh * 16 + lr) * 512 + ch * 32 + lk * 8);
      oc = __builtin_amdgcn_mfma_f32_16x16x32_bf16(ap, bv8, oc, 0, 0, 0);
    }
    #pragma unroll
    for (int r = 0; r < 4; r++)
      o_bf[(rt * 16 + lk * 4 + r) * 256 + head * 32 + dh * 16 + lr] = f2bf(oc[r]);
  }
}

// ---------- tail: 256 blocks x 512, 2 rows/block ----------
__global__ __launch_bounds__(512) void tail_kernel(
    const short* __restrict__ o_bf, float* __restrict__ h,
    const short* __restrict__ AoT_l, const float* __restrict__ bo_l,
    const float* __restrict__ ln2_s, const float* __restrict__ ln2_b,
    const short* __restrict__ A1T_l, const float* __restrict__ b1_l,
    const short* __restrict__ A2T_l, const float* __restrict__ b2_l,
    const float* __restrict__ ln1n_s, const float* __restrict__ ln1n_b,
    const short* __restrict__ Aqkv_n, const float* __restrict__ bq_n,
    const float* __restrict__ bk_n, const float* __restrict__ bv_n,
    short* __restrict__ q_bf, short* __restrict__ k_bf, short* __restrict__ vT_bf,
    int last) {
  __shared__ __align__(16) short Abuf[16 * ASTR];
  __shared__ __align__(16) short Bbuf[16 * ASTR];
  __shared__ __align__(16) float hbuf[2 * 256];
  int tid = threadIdx.x, bid = blockIdx.x;
  int w = tid >> 6, l = tid & 63, lr = l & 15, lk = l >> 4;
  int m0 = bid * 2;
  // zero pad rows 2..15
  for (int i = tid; i < 924; i += 512) {
    bf16x8 z = {};
    if (i < 462) *(bf16x8*)(Abuf + 2 * ASTR + i * 8) = z;
    else         *(bf16x8*)(Bbuf + 2 * ASTR + (i - 462) * 8) = z;
  }
  if (tid < 64) {
    int row = tid >> 5, j = tid & 31;
    *(bf16x8*)(Abuf + row * ASTR + j * 8) =
        *(const bf16x8*)(o_bf + (m0 + row) * 256 + j * 8);
  }
  __syncthreads();
  // O-proj + residual
  {
    f32x4 acc[2] = {};
    int nb = w * 32;
    for (int k0 = 0; k0 < 256; k0 += 32) {
      bf16x8 af = *(const bf16x8*)(Abuf + lr * ASTR + k0 + lk * 8);
      bf16x8 b0 = *(const bf16x8*)(AoT_l + (nb + lr) * 256 + k0 + lk * 8);
      bf16x8 b1f = *(const bf16x8*)(AoT_l + (nb + 16 + lr) * 256 + k0 + lk * 8);
      acc[0] = __builtin_amdgcn_mfma_f32_16x16x32_bf16(af, b0, acc[0], 0, 0, 0);
      acc[1] = __builtin_amdgcn_mfma_f32_16x16x32_bf16(af, b1f, acc[1], 0, 0, 0);
    }
    #pragma unroll
    for (int t = 0; t < 2; t++) {
      int n = nb + t * 16 + lr;
      #pragma unroll
      for (int r = 0; r < 4; r++) {
        int m = lk * 4 + r;
        if (m < 2) {
          float hv = h[(m0 + m) * 256 + n] + acc[t][r] + bo_l[n];
          hbuf[m * 256 + n] = hv;
          h[(m0 + m) * 256 + n] = hv;
        }
      }
    }
  }
  __syncthreads();
  // LN2 (waves 0-1)
  if (w < 2) {
    float4 v4 = *(const float4*)(hbuf + w * 256 + l * 4);
    float sum = v4.x + v4.y + v4.z + v4.w;
    #pragma unroll
    for (int o = 32; o; o >>= 1) sum += __shfl_xor(sum, o);
    float mean = sum * (1.f / 256.f);
    float dx = v4.x - mean, dy = v4.y - mean, dz = v4.z - mean, dw = v4.w - mean;
    float var = dx * dx + dy * dy + dz * dz + dw * dw;
    #pragma unroll
    for (int o = 32; o; o >>= 1) var += __shfl_xor(var, o);
    float inv = rsqrtf(var * (1.f / 256.f) + 1e-5f);
    const float4 sv = *(const float4*)(ln2_s + l * 4);
    const float4 bv4 = *(const float4*)(ln2_b + l * 4);
    bf16x4 o4;
    o4[0] = f2bf(dx * inv * sv.x + bv4.x);
    o4[1] = f2bf(dy * inv * sv.y + bv4.y);
    o4[2] = f2bf(dz * inv * sv.z + bv4.z);
    o4[3] = f2bf(dw * inv * sv.w + bv4.w);
    *(bf16x4*)(Abuf + w * ASTR + l * 4) = o4;
  }
  __syncthreads();
  // FFN1 + gelu
  {
    f32x4 acc[2] = {};
    int nb = w * 32;
    for (int k0 = 0; k0 < 256; k0 += 32) {
      bf16x8 af = *(const bf16x8*)(Abuf + lr * ASTR + k0 + lk * 8);
      bf16x8 b0 = *(const bf16x8*)(A1T_l + (nb + lr) * 256 + k0 + lk * 8);
      bf16x8 b1f = *(const bf16x8*)(A1T_l + (nb + 16 + lr) * 256 + k0 + lk * 8);
      acc[0] = __builtin_amdgcn_mfma_f32_16x16x32_bf16(af, b0, acc[0], 0, 0, 0);
      acc[1] = __builtin_amdgcn_mfma_f32_16x16x32_bf16(af, b1f, acc[1], 0, 0, 0);
    }
    #pragma unroll
    for (int t = 0; t < 2; t++) {
      int n = nb + t * 16 + lr;
      #pragma unroll
      for (int r = 0; r < 4; r++) {
        int m = lk * 4 + r;
        if (m < 2) {
          float val = acc[t][r] + b1_l[n];
          Bbuf[m * ASTR + n] =
              f2bf(0.5f * val * (1.f + erff(val * 0.70710678118654752f)));
        }
      }
    }
  }
  __syncthreads();
  // FFN2 + residual
  {
    f32x4 acc[2] = {};
    int nb = w * 32;
    for (int k0 = 0; k0 < 256; k0 += 32) {
      bf16x8 af = *(const bf16x8*)(Bbuf + lr * ASTR + k0 + lk * 8);
      bf16x8 b0 = *(const bf16x8*)(A2T_l + (nb + lr) * 256 + k0 + lk * 8);
      bf16x8 b1f = *(const bf16x8*)(A2T_l + (nb + 16 + lr) * 256 + k0 + lk * 8);
      acc[0] = __builtin_amdgcn_mfma_f32_16x16x32_bf16(af, b0, acc[0], 0, 0, 0);
      acc[1] = __builtin_amdgcn_mfma_f32_16x16x32_bf16(af, b1f, acc[1], 0, 0, 0);
    }
    #pragma unroll
    for (int t = 0; t < 2; t++) {
      int n = nb + t * 16 + lr;
      #pragma unroll
      for (int r = 0; r < 4; r++) {
        int m = lk * 4 + r;
        if (m < 2) {
          float hv = hbuf[m * 256 + n] + acc[t][r] + b2_l[n];
          h[(m0 + m) * 256 + n] = hv;
          hbuf[m * 256 + n] = hv;
        }
      }
    }
  }
  if (last) return;
  __syncthreads();
  // LN1 next (waves 0-1)
  if (w < 2) {
    float4 v4 = *(const float4*)(hbuf + w * 256 + l * 4);
    float sum = v4.x + v4.y + v4.z + v4.w;
    #pragma unroll
    for (int o = 32; o; o >>= 1) sum += __shfl_xor(sum, o);
    float mean = sum * (1.f / 256.f);
    float dx = v4.x - mean, dy = v4.y - mean, dz = v4.z - mean, dw = v4.w - mean;
    float var = dx * dx + dy * dy + dz * dz + dw * dw;
    #pragma unroll
    for (int o = 32; o; o >>= 1) var += __shfl_xor(var, o);
    float inv = rsqrtf(var * (1.f / 256.f) + 1e-5f);
    const float4 sv = *(const float4*)(ln1n_s + l * 4);
    const float4 bv4 = *(const float4*)(ln1n_b + l * 4);
    bf16x4 o4;
    o4[0] = f2bf(dx * inv * sv.x + bv4.x);
    o4[1] = f2bf(dy * inv * sv.y + bv4.y);
    o4[2] = f2bf(dz * inv * sv.z + bv4.z);
    o4[3] = f2bf(dw * inv * sv.w + bv4.w);
    *(bf16x4*)(Abuf + w * ASTR + l * 4) = o4;
  }
  __syncthreads();
  // QKV next layer
  {
    f32x4 acc[6] = {};
    int nb = w * 96;
    for (int k0 = 0; k0 < 256; k0 += 32) {
      bf16x8 af = *(const bf16x8*)(Abuf + lr * ASTR + k0 + lk * 8);
      #pragma unroll
      for (int t = 0; t < 6; t++) {
        bf16x8 bfr = *(const bf16x8*)(Aqkv_n + (nb + t * 16 + lr) * 256 + k0 + lk * 8);
        acc[t] = __builtin_amdgcn_mfma_f32_16x16x32_bf16(af, bfr, acc[t], 0, 0, 0);
      }
    }
    #pragma unroll
    for (int t = 0; t < 6; t++) {
      int n = nb + t * 16 + lr;
      #pragma unroll
      for (int r = 0; r < 4; r++) {
        int m = lk * 4 + r;
        if (m < 2) {
          int gm = m0 + m;
          float v = acc[t][r];
          if (n < 256) {
            q_bf[((n >> 5) * 512 + gm) * 32 + (n & 31)] = f2bf(v + bq_n[n] * QSCALE);
          } else if (n < 512) {
            int nn = n - 256;
            k_bf[((nn >> 5) * 512 + gm) * 32 + (nn & 31)] = f2bf(v + bk_n[nn]);
          } else {
            int nn = n - 512;
            vT_bf[nn * 512 + gm] = f2bf(v + bv_n[nn]);
          }
        }
      }
    }
  }
}

extern "C" void kernel_launch(void* const* d_in, const int* in_sizes, int n_in,
                              void* d_out, int out_size, void* d_ws, size_t ws_size,
                              hipStream_t stream) {
  const float* x             = (const float*)d_in[0];
  const int*   edge_encodes  = (const int*)d_in[2];
  const int*   edge_dist_enc = (const int*)d_in[3];
  const float* W_feat = (const float*)d_in[7];
  const float* b_feat = (const float*)d_in[8];
  const float* edge_emb      = (const float*)d_in[9];
  const float* edge_dist_emb = (const float*)d_in[10];
  const float* W_ee = (const float*)d_in[11];
  const float* b_ee = (const float*)d_in[12];
  const float* W_ed = (const float*)d_in[13];
  const float* b_ed = (const float*)d_in[14];
  const float* ln1_s = (const float*)d_in[15];
  const float* ln1_b = (const float*)d_in[16];
  const float* Wq = (const float*)d_in[17];
  const float* bq = (const float*)d_in[18];
  const float* Wk = (const float*)d_in[19];
  const float* bk = (const float*)d_in[20];
  const float* Wv = (const float*)d_in[21];
  const float* bv = (const float*)d_in[22];
  const float* Wo = (const float*)d_in[23];
  const float* bo = (const float*)d_in[24];
  const float* ln2_s = (const float*)d_in[25];
  const float* ln2_b = (const float*)d_in[26];
  const float* W1 = (const float*)d_in[27];
  const float* b1 = (const float*)d_in[28];
  const float* W2 = (const float*)d_in[29];
  const float* b2 = (const float*)d_in[30];

  float* h = (float*)d_out;
  char* base = (char*)d_ws;
  short* bias_bf = (short*)base;                       // 4 MB
  short* Aqkv = (short*)(base + 4194304);
  short* AoT  = (short*)(base + 6553600);
  short* A1T  = (short*)(base + 7340032);
  short* A2T  = (short*)(base + 8126464);
  short* WfT  = (short*)(base + 8912896);
  short* q_bf = (short*)(base + 9043968);
  short* k_bf = (short*)(base + 9306112);
  short* vT_bf= (short*)(base + 9568256);
  short* o_bf = (short*)(base + 9830400);
  float* eeP  = (float*)(base + 10092544);
  float* edP  = (float*)(base + 10093568);

  prep1_kernel<<<2528, 256, 0, stream>>>(
      Wq, Wk, Wv, Wo, W1, W2, W_feat,
      edge_emb, edge_dist_emb, W_ee, W_ed,
      Aqkv, AoT, A1T, A2T, WfT, eeP, edP);
  prep2_kernel<<<576, 512, 0, stream>>>(
      edge_encodes, edge_dist_enc, eeP, edP, b_ee, b_ed, bias_bf,
      x, WfT, b_feat, h, ln1_s, ln1_b, Aqkv, bq, bk, bv, q_bf, k_bf, vT_bf);

  for (int l = 0; l < NLAYER; l++) {
    attn_kernel<<<256, 256, 0, stream>>>(q_bf, k_bf, vT_bf, bias_bf, o_bf);
    int ln = (l < NLAYER - 1) ? l + 1 : l;
    tail_kernel<<<256, 512, 0, stream>>>(
        o_bf, h,
        AoT + l * 65536, bo + l * HD,
        ln2_s + l * HD, ln2_b + l * HD,
        A1T + l * 65536, b1 + l * HD,
        A2T + l * 65536, b2 + l * HD,
        ln1_s + ln * HD, ln1_b + ln * HD,
        Aqkv + ln * 196608, bq + ln * HD, bk + ln * HD, bv + ln * HD,
        q_bf, k_bf, vT_bf, l == NLAYER - 1);
  }
}

// Round 12
// 246.299 us; speedup vs baseline: 1.5610x; 1.0631x over previous
//
#include <hip/hip_runtime.h>
#include <math.h>

#define NN 512
#define HD 256
#define NLAYER 6
#define QSCALE 0.17677669529663687f
#define ASTR 264   // padded activation LDS stride (shorts)

typedef __attribute__((ext_vector_type(8))) short bf16x8;
typedef __attribute__((ext_vector_type(4))) short bf16x4;
typedef __attribute__((ext_vector_type(4))) float f32x4;

__device__ __forceinline__ short f2bf(float f) {
  union { float f; unsigned u; } v; v.f = f;
  unsigned r = (v.u + 0x7FFFu + ((v.u >> 16) & 1u)) >> 16;
  return (short)r;
}
__device__ __forceinline__ float bf2f(short s) {
  union { unsigned u; float f; } v; v.u = ((unsigned)(unsigned short)s) << 16;
  return v.f;
}

// ---------- prep1: wcast (blocks 0..2367) + proj (2368..2527) ----------
__global__ __launch_bounds__(256) void prep1_kernel(
    const float* __restrict__ Wq, const float* __restrict__ Wk,
    const float* __restrict__ Wv, const float* __restrict__ Wo,
    const float* __restrict__ W1, const float* __restrict__ W2,
    const float* __restrict__ Wf,
    const float* __restrict__ edge_emb, const float* __restrict__ edge_dist_emb,
    const float* __restrict__ W_ee, const float* __restrict__ W_ed,
    short* __restrict__ Aqkv, short* __restrict__ AoT,
    short* __restrict__ A1T, short* __restrict__ A2T, short* __restrict__ WfT,
    float* __restrict__ eeP, float* __restrict__ edP) {
  int b = blockIdx.x, tid = threadIdx.x;
  if (b < 2368) {
    __shared__ float tile[32][33];
    const float* src; short* dst; float scl = 1.f;
    int t;
    if (b < 2304) {
      int l = b / 384; int rr = b % 384; int mat = rr / 64; t = rr % 64;
      if      (mat == 0) { src = Wq + l * 65536; dst = Aqkv + l * 196608; scl = QSCALE; }
      else if (mat == 1) { src = Wk + l * 65536; dst = Aqkv + l * 196608 + 65536; }
      else if (mat == 2) { src = Wv + l * 65536; dst = Aqkv + l * 196608 + 131072; }
      else if (mat == 3) { src = Wo + l * 65536; dst = AoT + l * 65536; }
      else if (mat == 4) { src = W1 + l * 65536; dst = A1T + l * 65536; }
      else               { src = W2 + l * 65536; dst = A2T + l * 65536; }
    } else {
      src = Wf; dst = WfT; t = b - 2304;
    }
    int tr = t >> 3, tc = t & 7;
    int kl = tid >> 3, nl4 = (tid & 7) * 4;
    float4 v = *(const float4*)(src + (tr * 32 + kl) * 256 + tc * 32 + nl4);
    tile[kl][nl4 + 0] = v.x; tile[kl][nl4 + 1] = v.y;
    tile[kl][nl4 + 2] = v.z; tile[kl][nl4 + 3] = v.w;
    __syncthreads();
    int nl = tid >> 3, kl4 = (tid & 7) * 4;
    bf16x4 o;
    #pragma unroll
    for (int i = 0; i < 4; i++) o[i] = f2bf(tile[kl4 + i][nl] * scl);
    *(bf16x4*)(dst + (tc * 32 + nl) * 256 + tr * 32 + kl4) = o;
  } else {
    int r = b - 2368;
    const float* table; const float* W; float* out; int row;
    if (r < 32) { table = edge_emb;      W = W_ee; out = eeP; row = r; }
    else        { table = edge_dist_emb; W = W_ed; out = edP; row = r - 32; }
    int w = tid >> 6, l = tid & 63;
    __shared__ float sb[4];
    float val = table[row * HD + tid];
    float ss = val * val;
    #pragma unroll
    for (int o = 32; o; o >>= 1) ss += __shfl_xor(ss, o);
    if (l == 0) sb[w] = ss;
    __syncthreads();
    ss = sb[0] + sb[1] + sb[2] + sb[3];
    float n = sqrtf(ss);
    float sc = (n > 1.f) ? 1.f / (n + 1e-7f) : 1.f;
    float v = val * sc;
    __syncthreads();
    #pragma unroll
    for (int hh = 0; hh < 8; hh++) {
      float p = v * W[tid * 8 + hh];
      #pragma unroll
      for (int o = 32; o; o >>= 1) p += __shfl_xor(p, o);
      if (l == 0) sb[w] = p;
      __syncthreads();
      if (tid == 0) out[row * 8 + hh] = sb[0] + sb[1] + sb[2] + sb[3];
      __syncthreads();
    }
  }
}

// ---------- prep2: bias (blocks 0..511) + feat+LN1+QKV0 (512..575) ----------
__global__ __launch_bounds__(512) void prep2_kernel(
    const int* __restrict__ ee, const int* __restrict__ ed,
    const float* __restrict__ eeP, const float* __restrict__ edP,
    const float* __restrict__ b_ee, const float* __restrict__ b_ed,
    short* __restrict__ bias_bf,
    const float* __restrict__ x, const short* __restrict__ WfT,
    const float* __restrict__ b_feat, float* __restrict__ h,
    const float* __restrict__ ln1_s, const float* __restrict__ ln1_b,
    const short* __restrict__ Aqkv, const float* __restrict__ bq,
    const float* __restrict__ bk, const float* __restrict__ bv,
    short* __restrict__ q_bf, short* __restrict__ k_bf, short* __restrict__ vT_bf) {
  __shared__ __align__(16) char lds_raw[17000];
  int tid = threadIdx.x, bid = blockIdx.x;
  if (bid < 512) {
    float* seeP = (float*)lds_raw;
    float* sedP = seeP + 256;
    float* sbe  = sedP + 1024;
    float* sbd  = sbe + 8;
    if (tid < 256) seeP[tid] = eeP[tid];
    sedP[tid] = edP[tid]; sedP[tid + 512] = edP[tid + 512];
    if (tid < 8) { sbe[tid] = b_ee[tid]; sbd[tid] = b_ed[tid]; }
    __syncthreads();
    int idx = bid * 512 + tid;
    int e0 = ee[idx * 2], e1 = ee[idx * 2 + 1];
    int d = ed[idx];
    #pragma unroll
    for (int hh = 0; hh < 8; hh++) {
      bias_bf[hh * (NN * NN) + idx] = f2bf(
          0.5f * (seeP[e0 * 8 + hh] + seeP[e1 * 8 + hh]) + sbe[hh]
          + sedP[d * 8 + hh] + sbd[hh]);
    }
    return;
  }
  short* Abuf = (short*)lds_raw;                  // [16][ASTR]
  float* hbuf = (float*)(lds_raw + 8448);         // [8][256]
  int w = tid >> 6, l = tid & 63, lr = l & 15, lk = l >> 4;
  int m0 = (bid - 512) * 8;
  if (tid < 264) {
    bf16x8 z = {};
    *(bf16x8*)(Abuf + 8 * ASTR + tid * 8) = z;
  }
  {
    int row = tid >> 6, j = tid & 63;
    float4 v = *(const float4*)(x + (m0 + row) * 256 + j * 4);
    bf16x4 o4; o4[0] = f2bf(v.x); o4[1] = f2bf(v.y); o4[2] = f2bf(v.z); o4[3] = f2bf(v.w);
    *(bf16x4*)(Abuf + row * ASTR + j * 4) = o4;
  }
  __syncthreads();
  {
    f32x4 acc[2] = {};
    int nb = w * 32;
    #pragma unroll
    for (int k0 = 0; k0 < 256; k0 += 32) {
      bf16x8 af = *(const bf16x8*)(Abuf + lr * ASTR + k0 + lk * 8);
      bf16x8 b0 = *(const bf16x8*)(WfT + (nb + lr) * 256 + k0 + lk * 8);
      bf16x8 b1f = *(const bf16x8*)(WfT + (nb + 16 + lr) * 256 + k0 + lk * 8);
      acc[0] = __builtin_amdgcn_mfma_f32_16x16x32_bf16(af, b0, acc[0], 0, 0, 0);
      acc[1] = __builtin_amdgcn_mfma_f32_16x16x32_bf16(af, b1f, acc[1], 0, 0, 0);
    }
    #pragma unroll
    for (int t = 0; t < 2; t++) {
      int n = nb + t * 16 + lr;
      #pragma unroll
      for (int r = 0; r < 4; r++) {
        int m = lk * 4 + r;
        if (m < 8) {
          float v = acc[t][r] + b_feat[n];
          hbuf[m * 256 + n] = v;
          h[(m0 + m) * 256 + n] = v;
        }
      }
    }
  }
  __syncthreads();
  {  // LN1: wave w -> row w
    float4 v4 = *(const float4*)(hbuf + w * 256 + l * 4);
    float sum = v4.x + v4.y + v4.z + v4.w;
    #pragma unroll
    for (int o = 32; o; o >>= 1) sum += __shfl_xor(sum, o);
    float mean = sum * (1.f / 256.f);
    float dx = v4.x - mean, dy = v4.y - mean, dz = v4.z - mean, dw = v4.w - mean;
    float var = dx * dx + dy * dy + dz * dz + dw * dw;
    #pragma unroll
    for (int o = 32; o; o >>= 1) var += __shfl_xor(var, o);
    float inv = rsqrtf(var * (1.f / 256.f) + 1e-5f);
    const float4 sv = *(const float4*)(ln1_s + l * 4);
    const float4 bv4 = *(const float4*)(ln1_b + l * 4);
    bf16x4 o4;
    o4[0] = f2bf(dx * inv * sv.x + bv4.x);
    o4[1] = f2bf(dy * inv * sv.y + bv4.y);
    o4[2] = f2bf(dz * inv * sv.z + bv4.z);
    o4[3] = f2bf(dw * inv * sv.w + bv4.w);
    *(bf16x4*)(Abuf + w * ASTR + l * 4) = o4;
  }
  __syncthreads();
  {  // QKV layer 0
    f32x4 acc[6] = {};
    int nb = w * 96;
    #pragma unroll 2
    for (int k0 = 0; k0 < 256; k0 += 32) {
      bf16x8 af = *(const bf16x8*)(Abuf + lr * ASTR + k0 + lk * 8);
      #pragma unroll
      for (int t = 0; t < 6; t++) {
        bf16x8 bfr = *(const bf16x8*)(Aqkv + (nb + t * 16 + lr) * 256 + k0 + lk * 8);
        acc[t] = __builtin_amdgcn_mfma_f32_16x16x32_bf16(af, bfr, acc[t], 0, 0, 0);
      }
    }
    #pragma unroll
    for (int t = 0; t < 6; t++) {
      int n = nb + t * 16 + lr;
      #pragma unroll
      for (int r = 0; r < 4; r++) {
        int m = lk * 4 + r;
        if (m < 8) {
          int gm = m0 + m;
          float v = acc[t][r];
          if (n < 256) {
            q_bf[((n >> 5) * 512 + gm) * 32 + (n & 31)] = f2bf(v + bq[n] * QSCALE);
          } else if (n < 512) {
            int nn = n - 256;
            k_bf[((nn >> 5) * 512 + gm) * 32 + (nn & 31)] = f2bf(v + bk[nn]);
          } else {
            int nn = n - 512;
            vT_bf[nn * 512 + gm] = f2bf(v + bv[nn]);
          }
        }
      }
    }
  }
}

// ---------- attention: 256 blocks x 256 threads, 1 (head, rowtile16) ----------
__global__ __launch_bounds__(256) void attn_kernel(
    const short* __restrict__ q_bf, const short* __restrict__ k_bf,
    const short* __restrict__ vT_bf, const short* __restrict__ bias_bf,
    short* __restrict__ o_bf) {
  __shared__ __align__(16) short S[16 * 520];
  int tid = threadIdx.x, bid = blockIdx.x;
  int w = tid >> 6, l = tid & 63, lr = l & 15, lk = l >> 4;
  int head = bid >> 5, rt = bid & 31;
  // stage bias tile (coalesced)
  for (int i = tid; i < 1024; i += 256) {
    int row = i >> 6, grp = i & 63;
    *(bf16x8*)(S + row * 520 + grp * 8) =
        *(const bf16x8*)(bias_bf + (head * 512 + rt * 16 + row) * 512 + grp * 8);
  }
  bf16x8 aq = *(const bf16x8*)(q_bf + (head * 512 + rt * 16 + lr) * 32 + lk * 8);
  __syncthreads();
  // QK^T + bias: full unroll -> 8 K loads in flight
  {
    f32x4 sacc[8];
    #pragma unroll
    for (int j = 0; j < 8; j++) {
      int node0 = w * 128 + j * 16;
      bf16x8 bk8 = *(const bf16x8*)(k_bf + (head * 512 + node0 + lr) * 32 + lk * 8);
      f32x4 s = {};
      sacc[j] = __builtin_amdgcn_mfma_f32_16x16x32_bf16(aq, bk8, s, 0, 0, 0);
    }
    #pragma unroll
    for (int j = 0; j < 8; j++) {
      int gnode = w * 128 + j * 16 + lr;
      #pragma unroll
      for (int r = 0; r < 4; r++) {
        int row = lk * 4 + r;
        short* sp = S + row * 520 + gnode;
        *sp = f2bf(sacc[j][r] + bf2f(*sp));
      }
    }
  }
  __syncthreads();
  // softmax: 16 rows, 16 threads/row; vectorized (col = j*8 + t*128)
  {
    int row = tid >> 4, j = tid & 15;
    short* Srow = S + row * 520;
    float v[32];
    #pragma unroll
    for (int t = 0; t < 4; t++) {
      bf16x8 pk = *(const bf16x8*)(Srow + j * 8 + t * 128);
      #pragma unroll
      for (int e = 0; e < 8; e++) v[t * 8 + e] = bf2f(pk[e]);
    }
    float mx = -1e30f;
    #pragma unroll
    for (int i = 0; i < 32; i++) mx = fmaxf(mx, v[i]);
    #pragma unroll
    for (int o = 8; o; o >>= 1) mx = fmaxf(mx, __shfl_xor(mx, o, 16));
    float sum = 0.f;
    #pragma unroll
    for (int i = 0; i < 32; i++) { v[i] = __expf(v[i] - mx); sum += v[i]; }
    #pragma unroll
    for (int o = 8; o; o >>= 1) sum += __shfl_xor(sum, o, 16);
    float inv = 1.f / sum;
    #pragma unroll
    for (int t = 0; t < 4; t++) {
      bf16x8 pk;
      #pragma unroll
      for (int e = 0; e < 8; e++) pk[e] = f2bf(v[t * 8 + e] * inv);
      *(bf16x8*)(Srow + j * 8 + t * 128) = pk;
    }
  }
  __syncthreads();
  // PV: waves 0,1 -> dk halves; dual accumulators break the chain
  if (w < 2) {
    int dh = w;
    f32x4 oc0 = {}, oc1 = {};
    #pragma unroll
    for (int ch = 0; ch < 16; ch += 2) {
      bf16x8 ap0 = *(const bf16x8*)(S + lr * 520 + ch * 32 + lk * 8);
      bf16x8 bv0 = *(const bf16x8*)(vT_bf + (head * 32 + dh * 16 + lr) * 512 + ch * 32 + lk * 8);
      bf16x8 ap1 = *(const bf16x8*)(S + lr * 520 + (ch + 1) * 32 + lk * 8);
      bf16x8 bv1 = *(const bf16x8*)(vT_bf + (head * 32 + dh * 16 + lr) * 512 + (ch + 1) * 32 + lk * 8);
      oc0 = __builtin_amdgcn_mfma_f32_16x16x32_bf16(ap0, bv0, oc0, 0, 0, 0);
      oc1 = __builtin_amdgcn_mfma_f32_16x16x32_bf16(ap1, bv1, oc1, 0, 0, 0);
    }
    f32x4 oc = oc0 + oc1;
    #pragma unroll
    for (int r = 0; r < 4; r++)
      o_bf[(rt * 16 + lk * 4 + r) * 256 + head * 32 + dh * 16 + lr] = f2bf(oc[r]);
  }
}

// ---------- tail: 256 blocks x 512, 2 rows/block ----------
__global__ __launch_bounds__(512) void tail_kernel(
    const short* __restrict__ o_bf, float* __restrict__ h,
    const short* __restrict__ AoT_l, const float* __restrict__ bo_l,
    const float* __restrict__ ln2_s, const float* __restrict__ ln2_b,
    const short* __restrict__ A1T_l, const float* __restrict__ b1_l,
    const short* __restrict__ A2T_l, const float* __restrict__ b2_l,
    const float* __restrict__ ln1n_s, const float* __restrict__ ln1n_b,
    const short* __restrict__ Aqkv_n, const float* __restrict__ bq_n,
    const float* __restrict__ bk_n, const float* __restrict__ bv_n,
    short* __restrict__ q_bf, short* __restrict__ k_bf, short* __restrict__ vT_bf,
    int last) {
  __shared__ __align__(16) short Abuf[16 * ASTR];
  __shared__ __align__(16) short Bbuf[16 * ASTR];
  __shared__ __align__(16) float hbuf[2 * 256];
  int tid = threadIdx.x, bid = blockIdx.x;
  int w = tid >> 6, l = tid & 63, lr = l & 15, lk = l >> 4;
  int m0 = bid * 2;
  for (int i = tid; i < 924; i += 512) {
    bf16x8 z = {};
    if (i < 462) *(bf16x8*)(Abuf + 2 * ASTR + i * 8) = z;
    else         *(bf16x8*)(Bbuf + 2 * ASTR + (i - 462) * 8) = z;
  }
  if (tid < 64) {
    int row = tid >> 5, j = tid & 31;
    *(bf16x8*)(Abuf + row * ASTR + j * 8) =
        *(const bf16x8*)(o_bf + (m0 + row) * 256 + j * 8);
  }
  __syncthreads();
  // O-proj + residual (full unroll: 16 B-loads in flight)
  {
    f32x4 acc[2] = {};
    int nb = w * 32;
    #pragma unroll
    for (int k0 = 0; k0 < 256; k0 += 32) {
      bf16x8 af = *(const bf16x8*)(Abuf + lr * ASTR + k0 + lk * 8);
      bf16x8 b0 = *(const bf16x8*)(AoT_l + (nb + lr) * 256 + k0 + lk * 8);
      bf16x8 b1f = *(const bf16x8*)(AoT_l + (nb + 16 + lr) * 256 + k0 + lk * 8);
      acc[0] = __builtin_amdgcn_mfma_f32_16x16x32_bf16(af, b0, acc[0], 0, 0, 0);
      acc[1] = __builtin_amdgcn_mfma_f32_16x16x32_bf16(af, b1f, acc[1], 0, 0, 0);
    }
    #pragma unroll
    for (int t = 0; t < 2; t++) {
      int n = nb + t * 16 + lr;
      #pragma unroll
      for (int r = 0; r < 4; r++) {
        int m = lk * 4 + r;
        if (m < 2) {
          float hv = h[(m0 + m) * 256 + n] + acc[t][r] + bo_l[n];
          hbuf[m * 256 + n] = hv;
          h[(m0 + m) * 256 + n] = hv;
        }
      }
    }
  }
  __syncthreads();
  // LN2 (waves 0-1)
  if (w < 2) {
    float4 v4 = *(const float4*)(hbuf + w * 256 + l * 4);
    float sum = v4.x + v4.y + v4.z + v4.w;
    #pragma unroll
    for (int o = 32; o; o >>= 1) sum += __shfl_xor(sum, o);
    float mean = sum * (1.f / 256.f);
    float dx = v4.x - mean, dy = v4.y - mean, dz = v4.z - mean, dw = v4.w - mean;
    float var = dx * dx + dy * dy + dz * dz + dw * dw;
    #pragma unroll
    for (int o = 32; o; o >>= 1) var += __shfl_xor(var, o);
    float inv = rsqrtf(var * (1.f / 256.f) + 1e-5f);
    const float4 sv = *(const float4*)(ln2_s + l * 4);
    const float4 bv4 = *(const float4*)(ln2_b + l * 4);
    bf16x4 o4;
    o4[0] = f2bf(dx * inv * sv.x + bv4.x);
    o4[1] = f2bf(dy * inv * sv.y + bv4.y);
    o4[2] = f2bf(dz * inv * sv.z + bv4.z);
    o4[3] = f2bf(dw * inv * sv.w + bv4.w);
    *(bf16x4*)(Abuf + w * ASTR + l * 4) = o4;
  }
  __syncthreads();
  // FFN1 + gelu
  {
    f32x4 acc[2] = {};
    int nb = w * 32;
    #pragma unroll
    for (int k0 = 0; k0 < 256; k0 += 32) {
      bf16x8 af = *(const bf16x8*)(Abuf + lr * ASTR + k0 + lk * 8);
      bf16x8 b0 = *(const bf16x8*)(A1T_l + (nb + lr) * 256 + k0 + lk * 8);
      bf16x8 b1f = *(const bf16x8*)(A1T_l + (nb + 16 + lr) * 256 + k0 + lk * 8);
      acc[0] = __builtin_amdgcn_mfma_f32_16x16x32_bf16(af, b0, acc[0], 0, 0, 0);
      acc[1] = __builtin_amdgcn_mfma_f32_16x16x32_bf16(af, b1f, acc[1], 0, 0, 0);
    }
    #pragma unroll
    for (int t = 0; t < 2; t++) {
      int n = nb + t * 16 + lr;
      #pragma unroll
      for (int r = 0; r < 4; r++) {
        int m = lk * 4 + r;
        if (m < 2) {
          float val = acc[t][r] + b1_l[n];
          Bbuf[m * ASTR + n] =
              f2bf(0.5f * val * (1.f + erff(val * 0.70710678118654752f)));
        }
      }
    }
  }
  __syncthreads();
  // FFN2 + residual
  {
    f32x4 acc[2] = {};
    int nb = w * 32;
    #pragma unroll
    for (int k0 = 0; k0 < 256; k0 += 32) {
      bf16x8 af = *(const bf16x8*)(Bbuf + lr * ASTR + k0 + lk * 8);
      bf16x8 b0 = *(const bf16x8*)(A2T_l + (nb + lr) * 256 + k0 + lk * 8);
      bf16x8 b1f = *(const bf16x8*)(A2T_l + (nb + 16 + lr) * 256 + k0 + lk * 8);
      acc[0] = __builtin_amdgcn_mfma_f32_16x16x32_bf16(af, b0, acc[0], 0, 0, 0);
      acc[1] = __builtin_amdgcn_mfma_f32_16x16x32_bf16(af, b1f, acc[1], 0, 0, 0);
    }
    #pragma unroll
    for (int t = 0; t < 2; t++) {
      int n = nb + t * 16 + lr;
      #pragma unroll
      for (int r = 0; r < 4; r++) {
        int m = lk * 4 + r;
        if (m < 2) {
          float hv = hbuf[m * 256 + n] + acc[t][r] + b2_l[n];
          h[(m0 + m) * 256 + n] = hv;
          hbuf[m * 256 + n] = hv;
        }
      }
    }
  }
  if (last) return;
  __syncthreads();
  // LN1 next (waves 0-1)
  if (w < 2) {
    float4 v4 = *(const float4*)(hbuf + w * 256 + l * 4);
    float sum = v4.x + v4.y + v4.z + v4.w;
    #pragma unroll
    for (int o = 32; o; o >>= 1) sum += __shfl_xor(sum, o);
    float mean = sum * (1.f / 256.f);
    float dx = v4.x - mean, dy = v4.y - mean, dz = v4.z - mean, dw = v4.w - mean;
    float var = dx * dx + dy * dy + dz * dz + dw * dw;
    #pragma unroll
    for (int o = 32; o; o >>= 1) var += __shfl_xor(var, o);
    float inv = rsqrtf(var * (1.f / 256.f) + 1e-5f);
    const float4 sv = *(const float4*)(ln1n_s + l * 4);
    const float4 bv4 = *(const float4*)(ln1n_b + l * 4);
    bf16x4 o4;
    o4[0] = f2bf(dx * inv * sv.x + bv4.x);
    o4[1] = f2bf(dy * inv * sv.y + bv4.y);
    o4[2] = f2bf(dz * inv * sv.z + bv4.z);
    o4[3] = f2bf(dw * inv * sv.w + bv4.w);
    *(bf16x4*)(Abuf + w * ASTR + l * 4) = o4;
  }
  __syncthreads();
  // QKV next layer
  {
    f32x4 acc[6] = {};
    int nb = w * 96;
    #pragma unroll 2
    for (int k0 = 0; k0 < 256; k0 += 32) {
      bf16x8 af = *(const bf16x8*)(Abuf + lr * ASTR + k0 + lk * 8);
      #pragma unroll
      for (int t = 0; t < 6; t++) {
        bf16x8 bfr = *(const bf16x8*)(Aqkv_n + (nb + t * 16 + lr) * 256 + k0 + lk * 8);
        acc[t] = __builtin_amdgcn_mfma_f32_16x16x32_bf16(af, bfr, acc[t], 0, 0, 0);
      }
    }
    #pragma unroll
    for (int t = 0; t < 6; t++) {
      int n = nb + t * 16 + lr;
      #pragma unroll
      for (int r = 0; r < 4; r++) {
        int m = lk * 4 + r;
        if (m < 2) {
          int gm = m0 + m;
          float v = acc[t][r];
          if (n < 256) {
            q_bf[((n >> 5) * 512 + gm) * 32 + (n & 31)] = f2bf(v + bq_n[n] * QSCALE);
          } else if (n < 512) {
            int nn = n - 256;
            k_bf[((nn >> 5) * 512 + gm) * 32 + (nn & 31)] = f2bf(v + bk_n[nn]);
          } else {
            int nn = n - 512;
            vT_bf[nn * 512 + gm] = f2bf(v + bv_n[nn]);
          }
        }
      }
    }
  }
}

extern "C" void kernel_launch(void* const* d_in, const int* in_sizes, int n_in,
                              void* d_out, int out_size, void* d_ws, size_t ws_size,
                              hipStream_t stream) {
  const float* x             = (const float*)d_in[0];
  const int*   edge_encodes  = (const int*)d_in[2];
  const int*   edge_dist_enc = (const int*)d_in[3];
  const float* W_feat = (const float*)d_in[7];
  const float* b_feat = (const float*)d_in[8];
  const float* edge_emb      = (const float*)d_in[9];
  const float* edge_dist_emb = (const float*)d_in[10];
  const float* W_ee = (const float*)d_in[11];
  const float* b_ee = (const float*)d_in[12];
  const float* W_ed = (const float*)d_in[13];
  const float* b_ed = (const float*)d_in[14];
  const float* ln1_s = (const float*)d_in[15];
  const float* ln1_b = (const float*)d_in[16];
  const float* Wq = (const float*)d_in[17];
  const float* bq = (const float*)d_in[18];
  const float* Wk = (const float*)d_in[19];
  const float* bk = (const float*)d_in[20];
  const float* Wv = (const float*)d_in[21];
  const float* bv = (const float*)d_in[22];
  const float* Wo = (const float*)d_in[23];
  const float* bo = (const float*)d_in[24];
  const float* ln2_s = (const float*)d_in[25];
  const float* ln2_b = (const float*)d_in[26];
  const float* W1 = (const float*)d_in[27];
  const float* b1 = (const float*)d_in[28];
  const float* W2 = (const float*)d_in[29];
  const float* b2 = (const float*)d_in[30];

  float* h = (float*)d_out;
  char* base = (char*)d_ws;
  short* bias_bf = (short*)base;                       // 4 MB
  short* Aqkv = (short*)(base + 4194304);
  short* AoT  = (short*)(base + 6553600);
  short* A1T  = (short*)(base + 7340032);
  short* A2T  = (short*)(base + 8126464);
  short* WfT  = (short*)(base + 8912896);
  short* q_bf = (short*)(base + 9043968);
  short* k_bf = (short*)(base + 9306112);
  short* vT_bf= (short*)(base + 9568256);
  short* o_bf = (short*)(base + 9830400);
  float* eeP  = (float*)(base + 10092544);
  float* edP  = (float*)(base + 10093568);

  prep1_kernel<<<2528, 256, 0, stream>>>(
      Wq, Wk, Wv, Wo, W1, W2, W_feat,
      edge_emb, edge_dist_emb, W_ee, W_ed,
      Aqkv, AoT, A1T, A2T, WfT, eeP, edP);
  prep2_kernel<<<576, 512, 0, stream>>>(
      edge_encodes, edge_dist_enc, eeP, edP, b_ee, b_ed, bias_bf,
      x, WfT, b_feat, h, ln1_s, ln1_b, Aqkv, bq, bk, bv, q_bf, k_bf, vT_bf);

  for (int l = 0; l < NLAYER; l++) {
    attn_kernel<<<256, 256, 0, stream>>>(q_bf, k_bf, vT_bf, bias_bf, o_bf);
    int ln = (l < NLAYER - 1) ? l + 1 : l;
    tail_kernel<<<256, 512, 0, stream>>>(
        o_bf, h,
        AoT + l * 65536, bo + l * HD,
        ln2_s + l * HD, ln2_b + l * HD,
        A1T + l * 65536, b1 + l * HD,
        A2T + l * 65536, b2 + l * HD,
        ln1_s + ln * HD, ln1_b + ln * HD,
        Aqkv + ln * 196608, bq + ln * HD, bk + ln * HD, bv + ln * HD,
        q_bf, k_bf, vT_bf, l == NLAYER - 1);
  }
}

// Round 13
// 224.728 us; speedup vs baseline: 1.7108x; 1.0960x over previous
//
#include <hip/hip_runtime.h>
#include <math.h>

#define NN 512
#define HD 256
#define NLAYER 6
#define QSCALE 0.17677669529663687f
#define ASTR 264   // padded activation LDS stride (shorts)

typedef __attribute__((ext_vector_type(8))) short bf16x8;
typedef __attribute__((ext_vector_type(4))) short bf16x4;
typedef __attribute__((ext_vector_type(4))) float f32x4;

__device__ __forceinline__ short f2bf(float f) {
  union { float f; unsigned u; } v; v.f = f;
  unsigned r = (v.u + 0x7FFFu + ((v.u >> 16) & 1u)) >> 16;
  return (short)r;
}
__device__ __forceinline__ float bf2f(short s) {
  union { unsigned u; float f; } v; v.u = ((unsigned)(unsigned short)s) << 16;
  return v.f;
}

// ---------- prep1: wcast (blocks 0..2367) + proj (2368..2527) ----------
__global__ __launch_bounds__(256) void prep1_kernel(
    const float* __restrict__ Wq, const float* __restrict__ Wk,
    const float* __restrict__ Wv, const float* __restrict__ Wo,
    const float* __restrict__ W1, const float* __restrict__ W2,
    const float* __restrict__ Wf,
    const float* __restrict__ edge_emb, const float* __restrict__ edge_dist_emb,
    const float* __restrict__ W_ee, const float* __restrict__ W_ed,
    short* __restrict__ Aqkv, short* __restrict__ AoT,
    short* __restrict__ A1T, short* __restrict__ A2T, short* __restrict__ WfT,
    float* __restrict__ eeP, float* __restrict__ edP) {
  int b = blockIdx.x, tid = threadIdx.x;
  if (b < 2368) {
    __shared__ float tile[32][33];
    const float* src; short* dst; float scl = 1.f;
    int t;
    if (b < 2304) {
      int l = b / 384; int rr = b % 384; int mat = rr / 64; t = rr % 64;
      if      (mat == 0) { src = Wq + l * 65536; dst = Aqkv + l * 196608; scl = QSCALE; }
      else if (mat == 1) { src = Wk + l * 65536; dst = Aqkv + l * 196608 + 65536; }
      else if (mat == 2) { src = Wv + l * 65536; dst = Aqkv + l * 196608 + 131072; }
      else if (mat == 3) { src = Wo + l * 65536; dst = AoT + l * 65536; }
      else if (mat == 4) { src = W1 + l * 65536; dst = A1T + l * 65536; }
      else               { src = W2 + l * 65536; dst = A2T + l * 65536; }
    } else {
      src = Wf; dst = WfT; t = b - 2304;
    }
    int tr = t >> 3, tc = t & 7;
    int kl = tid >> 3, nl4 = (tid & 7) * 4;
    float4 v = *(const float4*)(src + (tr * 32 + kl) * 256 + tc * 32 + nl4);
    tile[kl][nl4 + 0] = v.x; tile[kl][nl4 + 1] = v.y;
    tile[kl][nl4 + 2] = v.z; tile[kl][nl4 + 3] = v.w;
    __syncthreads();
    int nl = tid >> 3, kl4 = (tid & 7) * 4;
    bf16x4 o;
    #pragma unroll
    for (int i = 0; i < 4; i++) o[i] = f2bf(tile[kl4 + i][nl] * scl);
    *(bf16x4*)(dst + (tc * 32 + nl) * 256 + tr * 32 + kl4) = o;
  } else {
    int r = b - 2368;
    const float* table; const float* W; float* out; int row;
    if (r < 32) { table = edge_emb;      W = W_ee; out = eeP; row = r; }
    else        { table = edge_dist_emb; W = W_ed; out = edP; row = r - 32; }
    int w = tid >> 6, l = tid & 63;
    __shared__ float sb[4];
    float val = table[row * HD + tid];
    float ss = val * val;
    #pragma unroll
    for (int o = 32; o; o >>= 1) ss += __shfl_xor(ss, o);
    if (l == 0) sb[w] = ss;
    __syncthreads();
    ss = sb[0] + sb[1] + sb[2] + sb[3];
    float n = sqrtf(ss);
    float sc = (n > 1.f) ? 1.f / (n + 1e-7f) : 1.f;
    float v = val * sc;
    __syncthreads();
    #pragma unroll
    for (int hh = 0; hh < 8; hh++) {
      float p = v * W[tid * 8 + hh];
      #pragma unroll
      for (int o = 32; o; o >>= 1) p += __shfl_xor(p, o);
      if (l == 0) sb[w] = p;
      __syncthreads();
      if (tid == 0) out[row * 8 + hh] = sb[0] + sb[1] + sb[2] + sb[3];
      __syncthreads();
    }
  }
}

// ---------- prep2: bias (blocks 0..511) + feat+LN1+QKV0 (512..575) ----------
__global__ __launch_bounds__(512) void prep2_kernel(
    const int* __restrict__ ee, const int* __restrict__ ed,
    const float* __restrict__ eeP, const float* __restrict__ edP,
    const float* __restrict__ b_ee, const float* __restrict__ b_ed,
    short* __restrict__ bias_bf,
    const float* __restrict__ x, const short* __restrict__ WfT,
    const float* __restrict__ b_feat, float* __restrict__ h,
    const float* __restrict__ ln1_s, const float* __restrict__ ln1_b,
    const short* __restrict__ Aqkv, const float* __restrict__ bq,
    const float* __restrict__ bk, const float* __restrict__ bv,
    short* __restrict__ q_bf, short* __restrict__ k_bf, short* __restrict__ vT_bf) {
  __shared__ __align__(16) char lds_raw[17000];
  int tid = threadIdx.x, bid = blockIdx.x;
  if (bid < 512) {
    float* seeP = (float*)lds_raw;
    float* sedP = seeP + 256;
    float* sbe  = sedP + 1024;
    float* sbd  = sbe + 8;
    if (tid < 256) seeP[tid] = eeP[tid];
    sedP[tid] = edP[tid]; sedP[tid + 512] = edP[tid + 512];
    if (tid < 8) { sbe[tid] = b_ee[tid]; sbd[tid] = b_ed[tid]; }
    __syncthreads();
    int idx = bid * 512 + tid;
    int e0 = ee[idx * 2], e1 = ee[idx * 2 + 1];
    int d = ed[idx];
    #pragma unroll
    for (int hh = 0; hh < 8; hh++) {
      bias_bf[hh * (NN * NN) + idx] = f2bf(
          0.5f * (seeP[e0 * 8 + hh] + seeP[e1 * 8 + hh]) + sbe[hh]
          + sedP[d * 8 + hh] + sbd[hh]);
    }
    return;
  }
  short* Abuf = (short*)lds_raw;                  // [16][ASTR]
  float* hbuf = (float*)(lds_raw + 8448);         // [8][256]
  int w = tid >> 6, l = tid & 63, lr = l & 15, lk = l >> 4;
  int m0 = (bid - 512) * 8;
  if (tid < 264) {
    bf16x8 z = {};
    *(bf16x8*)(Abuf + 8 * ASTR + tid * 8) = z;
  }
  {
    int row = tid >> 6, j = tid & 63;
    float4 v = *(const float4*)(x + (m0 + row) * 256 + j * 4);
    bf16x4 o4; o4[0] = f2bf(v.x); o4[1] = f2bf(v.y); o4[2] = f2bf(v.z); o4[3] = f2bf(v.w);
    *(bf16x4*)(Abuf + row * ASTR + j * 4) = o4;
  }
  __syncthreads();
  {
    f32x4 acc[2] = {};
    int nb = w * 32;
    #pragma unroll
    for (int k0 = 0; k0 < 256; k0 += 32) {
      bf16x8 af = *(const bf16x8*)(Abuf + lr * ASTR + k0 + lk * 8);
      bf16x8 b0 = *(const bf16x8*)(WfT + (nb + lr) * 256 + k0 + lk * 8);
      bf16x8 b1f = *(const bf16x8*)(WfT + (nb + 16 + lr) * 256 + k0 + lk * 8);
      acc[0] = __builtin_amdgcn_mfma_f32_16x16x32_bf16(af, b0, acc[0], 0, 0, 0);
      acc[1] = __builtin_amdgcn_mfma_f32_16x16x32_bf16(af, b1f, acc[1], 0, 0, 0);
    }
    #pragma unroll
    for (int t = 0; t < 2; t++) {
      int n = nb + t * 16 + lr;
      #pragma unroll
      for (int r = 0; r < 4; r++) {
        int m = lk * 4 + r;
        if (m < 8) {
          float v = acc[t][r] + b_feat[n];
          hbuf[m * 256 + n] = v;
          h[(m0 + m) * 256 + n] = v;
        }
      }
    }
  }
  __syncthreads();
  {  // LN1: wave w -> row w
    float4 v4 = *(const float4*)(hbuf + w * 256 + l * 4);
    float sum = v4.x + v4.y + v4.z + v4.w;
    #pragma unroll
    for (int o = 32; o; o >>= 1) sum += __shfl_xor(sum, o);
    float mean = sum * (1.f / 256.f);
    float dx = v4.x - mean, dy = v4.y - mean, dz = v4.z - mean, dw = v4.w - mean;
    float var = dx * dx + dy * dy + dz * dz + dw * dw;
    #pragma unroll
    for (int o = 32; o; o >>= 1) var += __shfl_xor(var, o);
    float inv = rsqrtf(var * (1.f / 256.f) + 1e-5f);
    const float4 sv = *(const float4*)(ln1_s + l * 4);
    const float4 bv4 = *(const float4*)(ln1_b + l * 4);
    bf16x4 o4;
    o4[0] = f2bf(dx * inv * sv.x + bv4.x);
    o4[1] = f2bf(dy * inv * sv.y + bv4.y);
    o4[2] = f2bf(dz * inv * sv.z + bv4.z);
    o4[3] = f2bf(dw * inv * sv.w + bv4.w);
    *(bf16x4*)(Abuf + w * ASTR + l * 4) = o4;
  }
  __syncthreads();
  {  // QKV layer 0
    f32x4 acc[6] = {};
    int nb = w * 96;
    #pragma unroll 2
    for (int k0 = 0; k0 < 256; k0 += 32) {
      bf16x8 af = *(const bf16x8*)(Abuf + lr * ASTR + k0 + lk * 8);
      #pragma unroll
      for (int t = 0; t < 6; t++) {
        bf16x8 bfr = *(const bf16x8*)(Aqkv + (nb + t * 16 + lr) * 256 + k0 + lk * 8);
        acc[t] = __builtin_amdgcn_mfma_f32_16x16x32_bf16(af, bfr, acc[t], 0, 0, 0);
      }
    }
    #pragma unroll
    for (int t = 0; t < 6; t++) {
      int n = nb + t * 16 + lr;
      #pragma unroll
      for (int r = 0; r < 4; r++) {
        int m = lk * 4 + r;
        if (m < 8) {
          int gm = m0 + m;
          float v = acc[t][r];
          if (n < 256) {
            q_bf[((n >> 5) * 512 + gm) * 32 + (n & 31)] = f2bf(v + bq[n] * QSCALE);
          } else if (n < 512) {
            int nn = n - 256;
            k_bf[((nn >> 5) * 512 + gm) * 32 + (nn & 31)] = f2bf(v + bk[nn]);
          } else {
            int nn = n - 512;
            vT_bf[nn * 512 + gm] = f2bf(v + bv[nn]);
          }
        }
      }
    }
  }
}

// ---------- attention: 256 blocks x 512 threads, 1 (head, rowtile16) ----------
__global__ __launch_bounds__(512) void attn_kernel(
    const short* __restrict__ q_bf, const short* __restrict__ k_bf,
    const short* __restrict__ vT_bf, const short* __restrict__ bias_bf,
    short* __restrict__ o_bf) {
  __shared__ __align__(16) short S[16 * 520];
  int tid = threadIdx.x, bid = blockIdx.x;
  int w = tid >> 6, l = tid & 63, lr = l & 15, lk = l >> 4;
  int head = bid >> 5, rt = bid & 31;
  // stage bias tile (coalesced, 2 iters)
  #pragma unroll
  for (int i = tid; i < 1024; i += 512) {
    int row = i >> 6, grp = i & 63;
    *(bf16x8*)(S + row * 520 + grp * 8) =
        *(const bf16x8*)(bias_bf + (head * 512 + rt * 16 + row) * 512 + grp * 8);
  }
  bf16x8 aq = *(const bf16x8*)(q_bf + (head * 512 + rt * 16 + lr) * 32 + lk * 8);
  __syncthreads();
  // QK^T + bias: wave w covers nodes w*64..+63 (4 unrolled MFMAs)
  {
    f32x4 sacc[4];
    #pragma unroll
    for (int j = 0; j < 4; j++) {
      int node0 = w * 64 + j * 16;
      bf16x8 bk8 = *(const bf16x8*)(k_bf + (head * 512 + node0 + lr) * 32 + lk * 8);
      f32x4 s = {};
      sacc[j] = __builtin_amdgcn_mfma_f32_16x16x32_bf16(aq, bk8, s, 0, 0, 0);
    }
    #pragma unroll
    for (int j = 0; j < 4; j++) {
      int gnode = w * 64 + j * 16 + lr;
      #pragma unroll
      for (int r = 0; r < 4; r++) {
        int row = lk * 4 + r;
        short* sp = S + row * 520 + gnode;
        *sp = f2bf(sacc[j][r] + bf2f(*sp));
      }
    }
  }
  __syncthreads();
  // softmax: 16 rows, 32 threads/row; vectorized (col = j*8 + t*256)
  {
    int row = tid >> 5, j = tid & 31;
    short* Srow = S + row * 520;
    float v[16];
    #pragma unroll
    for (int t = 0; t < 2; t++) {
      bf16x8 pk = *(const bf16x8*)(Srow + j * 8 + t * 256);
      #pragma unroll
      for (int e = 0; e < 8; e++) v[t * 8 + e] = bf2f(pk[e]);
    }
    float mx = -1e30f;
    #pragma unroll
    for (int i = 0; i < 16; i++) mx = fmaxf(mx, v[i]);
    #pragma unroll
    for (int o = 16; o; o >>= 1) mx = fmaxf(mx, __shfl_xor(mx, o, 32));
    float sum = 0.f;
    #pragma unroll
    for (int i = 0; i < 16; i++) { v[i] = __expf(v[i] - mx); sum += v[i]; }
    #pragma unroll
    for (int o = 16; o; o >>= 1) sum += __shfl_xor(sum, o, 32);
    float inv = 1.f / sum;
    #pragma unroll
    for (int t = 0; t < 2; t++) {
      bf16x8 pk;
      #pragma unroll
      for (int e = 0; e < 8; e++) pk[e] = f2bf(v[t * 8 + e] * inv);
      *(bf16x8*)(Srow + j * 8 + t * 256) = pk;
    }
  }
  __syncthreads();
  // PV: waves 0,1 -> dk halves; dual accumulators
  if (w < 2) {
    int dh = w;
    f32x4 oc0 = {}, oc1 = {};
    #pragma unroll
    for (int ch = 0; ch < 16; ch += 2) {
      bf16x8 ap0 = *(const bf16x8*)(S + lr * 520 + ch * 32 + lk * 8);
      bf16x8 bv0 = *(const bf16x8*)(vT_bf + (head * 32 + dh * 16 + lr) * 512 + ch * 32 + lk * 8);
      bf16x8 ap1 = *(const bf16x8*)(S + lr * 520 + (ch + 1) * 32 + lk * 8);
      bf16x8 bv1 = *(const bf16x8*)(vT_bf + (head * 32 + dh * 16 + lr) * 512 + (ch + 1) * 32 + lk * 8);
      oc0 = __builtin_amdgcn_mfma_f32_16x16x32_bf16(ap0, bv0, oc0, 0, 0, 0);
      oc1 = __builtin_amdgcn_mfma_f32_16x16x32_bf16(ap1, bv1, oc1, 0, 0, 0);
    }
    f32x4 oc = oc0 + oc1;
    #pragma unroll
    for (int r = 0; r < 4; r++)
      o_bf[(rt * 16 + lk * 4 + r) * 256 + head * 32 + dh * 16 + lr] = f2bf(oc[r]);
  }
}

// ---------- tail: 256 blocks x 1024 threads, 2 rows/block ----------
__global__ __launch_bounds__(1024) void tail_kernel(
    const short* __restrict__ o_bf, float* __restrict__ h,
    const short* __restrict__ AoT_l, const float* __restrict__ bo_l,
    const float* __restrict__ ln2_s, const float* __restrict__ ln2_b,
    const short* __restrict__ A1T_l, const float* __restrict__ b1_l,
    const short* __restrict__ A2T_l, const float* __restrict__ b2_l,
    const float* __restrict__ ln1n_s, const float* __restrict__ ln1n_b,
    const short* __restrict__ Aqkv_n, const float* __restrict__ bq_n,
    const float* __restrict__ bk_n, const float* __restrict__ bv_n,
    short* __restrict__ q_bf, short* __restrict__ k_bf, short* __restrict__ vT_bf,
    int last) {
  __shared__ __align__(16) short Abuf[16 * ASTR];
  __shared__ __align__(16) short Bbuf[16 * ASTR];
  __shared__ __align__(16) float hbuf[2 * 256];
  int tid = threadIdx.x, bid = blockIdx.x;
  int w = tid >> 6, l = tid & 63, lr = l & 15, lk = l >> 4;
  int m0 = bid * 2;
  for (int i = tid; i < 924; i += 1024) {
    bf16x8 z = {};
    if (i < 462) *(bf16x8*)(Abuf + 2 * ASTR + i * 8) = z;
    else         *(bf16x8*)(Bbuf + 2 * ASTR + (i - 462) * 8) = z;
  }
  if (tid < 64) {
    int row = tid >> 5, j = tid & 31;
    *(bf16x8*)(Abuf + row * ASTR + j * 8) =
        *(const bf16x8*)(o_bf + (m0 + row) * 256 + j * 8);
  }
  __syncthreads();
  // O-proj + residual: wave w -> 16 cols
  {
    f32x4 acc = {};
    int nb = w * 16;
    #pragma unroll
    for (int k0 = 0; k0 < 256; k0 += 32) {
      bf16x8 af = *(const bf16x8*)(Abuf + lr * ASTR + k0 + lk * 8);
      bf16x8 b0 = *(const bf16x8*)(AoT_l + (nb + lr) * 256 + k0 + lk * 8);
      acc = __builtin_amdgcn_mfma_f32_16x16x32_bf16(af, b0, acc, 0, 0, 0);
    }
    int n = nb + lr;
    #pragma unroll
    for (int r = 0; r < 4; r++) {
      int m = lk * 4 + r;
      if (m < 2) {
        float hv = h[(m0 + m) * 256 + n] + acc[r] + bo_l[n];
        hbuf[m * 256 + n] = hv;
        h[(m0 + m) * 256 + n] = hv;
      }
    }
  }
  __syncthreads();
  // LN2 (waves 0-1)
  if (w < 2) {
    float4 v4 = *(const float4*)(hbuf + w * 256 + l * 4);
    float sum = v4.x + v4.y + v4.z + v4.w;
    #pragma unroll
    for (int o = 32; o; o >>= 1) sum += __shfl_xor(sum, o);
    float mean = sum * (1.f / 256.f);
    float dx = v4.x - mean, dy = v4.y - mean, dz = v4.z - mean, dw = v4.w - mean;
    float var = dx * dx + dy * dy + dz * dz + dw * dw;
    #pragma unroll
    for (int o = 32; o; o >>= 1) var += __shfl_xor(var, o);
    float inv = rsqrtf(var * (1.f / 256.f) + 1e-5f);
    const float4 sv = *(const float4*)(ln2_s + l * 4);
    const float4 bv4 = *(const float4*)(ln2_b + l * 4);
    bf16x4 o4;
    o4[0] = f2bf(dx * inv * sv.x + bv4.x);
    o4[1] = f2bf(dy * inv * sv.y + bv4.y);
    o4[2] = f2bf(dz * inv * sv.z + bv4.z);
    o4[3] = f2bf(dw * inv * sv.w + bv4.w);
    *(bf16x4*)(Abuf + w * ASTR + l * 4) = o4;
  }
  __syncthreads();
  // FFN1 + gelu
  {
    f32x4 acc = {};
    int nb = w * 16;
    #pragma unroll
    for (int k0 = 0; k0 < 256; k0 += 32) {
      bf16x8 af = *(const bf16x8*)(Abuf + lr * ASTR + k0 + lk * 8);
      bf16x8 b0 = *(const bf16x8*)(A1T_l + (nb + lr) * 256 + k0 + lk * 8);
      acc = __builtin_amdgcn_mfma_f32_16x16x32_bf16(af, b0, acc, 0, 0, 0);
    }
    int n = nb + lr;
    #pragma unroll
    for (int r = 0; r < 4; r++) {
      int m = lk * 4 + r;
      if (m < 2) {
        float val = acc[r] + b1_l[n];
        Bbuf[m * ASTR + n] =
            f2bf(0.5f * val * (1.f + erff(val * 0.70710678118654752f)));
      }
    }
  }
  __syncthreads();
  // FFN2 + residual
  {
    f32x4 acc = {};
    int nb = w * 16;
    #pragma unroll
    for (int k0 = 0; k0 < 256; k0 += 32) {
      bf16x8 af = *(const bf16x8*)(Bbuf + lr * ASTR + k0 + lk * 8);
      bf16x8 b0 = *(const bf16x8*)(A2T_l + (nb + lr) * 256 + k0 + lk * 8);
      acc = __builtin_amdgcn_mfma_f32_16x16x32_bf16(af, b0, acc, 0, 0, 0);
    }
    int n = nb + lr;
    #pragma unroll
    for (int r = 0; r < 4; r++) {
      int m = lk * 4 + r;
      if (m < 2) {
        float hv = hbuf[m * 256 + n] + acc[r] + b2_l[n];
        h[(m0 + m) * 256 + n] = hv;
        hbuf[m * 256 + n] = hv;
      }
    }
  }
  if (last) return;
  __syncthreads();
  // LN1 next (waves 0-1)
  if (w < 2) {
    float4 v4 = *(const float4*)(hbuf + w * 256 + l * 4);
    float sum = v4.x + v4.y + v4.z + v4.w;
    #pragma unroll
    for (int o = 32; o; o >>= 1) sum += __shfl_xor(sum, o);
    float mean = sum * (1.f / 256.f);
    float dx = v4.x - mean, dy = v4.y - mean, dz = v4.z - mean, dw = v4.w - mean;
    float var = dx * dx + dy * dy + dz * dz + dw * dw;
    #pragma unroll
    for (int o = 32; o; o >>= 1) var += __shfl_xor(var, o);
    float inv = rsqrtf(var * (1.f / 256.f) + 1e-5f);
    const float4 sv = *(const float4*)(ln1n_s + l * 4);
    const float4 bv4 = *(const float4*)(ln1n_b + l * 4);
    bf16x4 o4;
    o4[0] = f2bf(dx * inv * sv.x + bv4.x);
    o4[1] = f2bf(dy * inv * sv.y + bv4.y);
    o4[2] = f2bf(dz * inv * sv.z + bv4.z);
    o4[3] = f2bf(dw * inv * sv.w + bv4.w);
    *(bf16x4*)(Abuf + w * ASTR + l * 4) = o4;
  }
  __syncthreads();
  // QKV next layer: wave w -> 48 cols
  {
    f32x4 acc[3] = {};
    int nb = w * 48;
    #pragma unroll 2
    for (int k0 = 0; k0 < 256; k0 += 32) {
      bf16x8 af = *(const bf16x8*)(Abuf + lr * ASTR + k0 + lk * 8);
      #pragma unroll
      for (int t = 0; t < 3; t++) {
        bf16x8 bfr = *(const bf16x8*)(Aqkv_n + (nb + t * 16 + lr) * 256 + k0 + lk * 8);
        acc[t] = __builtin_amdgcn_mfma_f32_16x16x32_bf16(af, bfr, acc[t], 0, 0, 0);
      }
    }
    #pragma unroll
    for (int t = 0; t < 3; t++) {
      int n = nb + t * 16 + lr;
      #pragma unroll
      for (int r = 0; r < 4; r++) {
        int m = lk * 4 + r;
        if (m < 2) {
          int gm = m0 + m;
          float v = acc[t][r];
          if (n < 256) {
            q_bf[((n >> 5) * 512 + gm) * 32 + (n & 31)] = f2bf(v + bq_n[n] * QSCALE);
          } else if (n < 512) {
            int nn = n - 256;
            k_bf[((nn >> 5) * 512 + gm) * 32 + (nn & 31)] = f2bf(v + bk_n[nn]);
          } else {
            int nn = n - 512;
            vT_bf[nn * 512 + gm] = f2bf(v + bv_n[nn]);
          }
        }
      }
    }
  }
}

extern "C" void kernel_launch(void* const* d_in, const int* in_sizes, int n_in,
                              void* d_out, int out_size, void* d_ws, size_t ws_size,
                              hipStream_t stream) {
  const float* x             = (const float*)d_in[0];
  const int*   edge_encodes  = (const int*)d_in[2];
  const int*   edge_dist_enc = (const int*)d_in[3];
  const float* W_feat = (const float*)d_in[7];
  const float* b_feat = (const float*)d_in[8];
  const float* edge_emb      = (const float*)d_in[9];
  const float* edge_dist_emb = (const float*)d_in[10];
  const float* W_ee = (const float*)d_in[11];
  const float* b_ee = (const float*)d_in[12];
  const float* W_ed = (const float*)d_in[13];
  const float* b_ed = (const float*)d_in[14];
  const float* ln1_s = (const float*)d_in[15];
  const float* ln1_b = (const float*)d_in[16];
  const float* Wq = (const float*)d_in[17];
  const float* bq = (const float*)d_in[18];
  const float* Wk = (const float*)d_in[19];
  const float* bk = (const float*)d_in[20];
  const float* Wv = (const float*)d_in[21];
  const float* bv = (const float*)d_in[22];
  const float* Wo = (const float*)d_in[23];
  const float* bo = (const float*)d_in[24];
  const float* ln2_s = (const float*)d_in[25];
  const float* ln2_b = (const float*)d_in[26];
  const float* W1 = (const float*)d_in[27];
  const float* b1 = (const float*)d_in[28];
  const float* W2 = (const float*)d_in[29];
  const float* b2 = (const float*)d_in[30];

  float* h = (float*)d_out;
  char* base = (char*)d_ws;
  short* bias_bf = (short*)base;                       // 4 MB
  short* Aqkv = (short*)(base + 4194304);
  short* AoT  = (short*)(base + 6553600);
  short* A1T  = (short*)(base + 7340032);
  short* A2T  = (short*)(base + 8126464);
  short* WfT  = (short*)(base + 8912896);
  short* q_bf = (short*)(base + 9043968);
  short* k_bf = (short*)(base + 9306112);
  short* vT_bf= (short*)(base + 9568256);
  short* o_bf = (short*)(base + 9830400);
  float* eeP  = (float*)(base + 10092544);
  float* edP  = (float*)(base + 10093568);

  prep1_kernel<<<2528, 256, 0, stream>>>(
      Wq, Wk, Wv, Wo, W1, W2, W_feat,
      edge_emb, edge_dist_emb, W_ee, W_ed,
      Aqkv, AoT, A1T, A2T, WfT, eeP, edP);
  prep2_kernel<<<576, 512, 0, stream>>>(
      edge_encodes, edge_dist_enc, eeP, edP, b_ee, b_ed, bias_bf,
      x, WfT, b_feat, h, ln1_s, ln1_b, Aqkv, bq, bk, bv, q_bf, k_bf, vT_bf);

  for (int l = 0; l < NLAYER; l++) {
    attn_kernel<<<256, 512, 0, stream>>>(q_bf, k_bf, vT_bf, bias_bf, o_bf);
    int ln = (l < NLAYER - 1) ? l + 1 : l;
    tail_kernel<<<256, 1024, 0, stream>>>(
        o_bf, h,
        AoT + l * 65536, bo + l * HD,
        ln2_s + l * HD, ln2_b + l * HD,
        A1T + l * 65536, b1 + l * HD,
        A2T + l * 65536, b2 + l * HD,
        ln1_s + ln * HD, ln1_b + ln * HD,
        Aqkv + ln * 196608, bq + ln * HD, bk + ln * HD, bv + ln * HD,
        q_bf, k_bf, vT_bf, l == NLAYER - 1);
  }
}